// Round 1
// baseline (1069.522 us; speedup 1.0000x reference)
//
#include <hip/hip_runtime.h>
#include <cstdint>

#define VV     50257
#define VPAD   50304
#define DMODEL 768
#define NLAYER 4
#define DINNER 1536
#define DSTATE 16
#define DCONV  4
#define BATCH  2
#define SEQ    512
#define MROWS  (BATCH*SEQ)   // 1024

typedef unsigned short u16;
typedef __attribute__((ext_vector_type(8))) short bf16x8;
typedef __attribute__((ext_vector_type(4))) float f32x4;

__device__ __forceinline__ u16 f2bf(float f) {
  unsigned u = __float_as_uint(f);
  u += 0x7fffu + ((u >> 16) & 1u);
  return (u16)(u >> 16);
}

// global -> LDS direct copy, 16B per lane. LDS dest is wave-uniform base + lane*16.
__device__ __forceinline__ void async16(const void* g, void* l) {
  auto gp = reinterpret_cast<const __attribute__((address_space(1))) unsigned int*>(
      reinterpret_cast<uintptr_t>(g));
  auto lp = reinterpret_cast<__attribute__((address_space(3))) unsigned int*>(
      reinterpret_cast<uintptr_t>(l));
  __builtin_amdgcn_global_load_lds(gp, lp, 16, 0, 0);
}

// ---------------------------------------------------------------- conversions
__global__ void cvt_kern(const float* __restrict__ src, u16* __restrict__ dst, int n4) {
  int i = blockIdx.x * blockDim.x + threadIdx.x;
  int stride = gridDim.x * blockDim.x;
  for (; i < n4; i += stride) {
    float4 v = *(const float4*)(src + (long)i * 4);
    ushort4 o; o.x = f2bf(v.x); o.y = f2bf(v.y); o.z = f2bf(v.z); o.w = f2bf(v.w);
    *(ushort4*)(dst + (long)i * 4) = o;
  }
}

__global__ void cvt_pad_kern(const float* __restrict__ src, u16* __restrict__ dst,
                             int nsrc4, int ntot4) {
  int i = blockIdx.x * blockDim.x + threadIdx.x;
  int stride = gridDim.x * blockDim.x;
  for (; i < ntot4; i += stride) {
    ushort4 o;
    if (i < nsrc4) {
      float4 v = *(const float4*)(src + (long)i * 4);
      o.x = f2bf(v.x); o.y = f2bf(v.y); o.z = f2bf(v.z); o.w = f2bf(v.w);
    } else {
      o.x = 0; o.y = 0; o.z = 0; o.w = 0;
    }
    *(ushort4*)(dst + (long)i * 4) = o;
  }
}

// ---------------------------------------------------------------- embedding
__global__ void embed_kern(const int* __restrict__ idx, const float* __restrict__ emb,
                           float* __restrict__ x, u16* __restrict__ xbf) {
  int i4 = blockIdx.x * blockDim.x + threadIdx.x;    // over MROWS * DMODEL/4
  if (i4 >= MROWS * (DMODEL / 4)) return;
  int r = i4 / (DMODEL / 4);
  int c = (i4 % (DMODEL / 4)) * 4;
  int id = idx[r];
  float4 v = *(const float4*)(emb + (long)id * DMODEL + c);
  *(float4*)(x + (long)r * DMODEL + c) = v;
  ushort4 o; o.x = f2bf(v.x); o.y = f2bf(v.y); o.z = f2bf(v.z); o.w = f2bf(v.w);
  *(ushort4*)(xbf + (long)r * DMODEL + c) = o;
}

// ---------------------------------------------------------------- bf16 BT-GEMM
// C[m,n] = sum_k A[m,k]*B[n,k]  (A: MxK bf16 row-major, B: NxK bf16 row-major)
// 128x128 tile, K-step 64, 4 waves (2x2), 16x16x32 bf16 MFMA.
// LDS XOR swizzle: LDS[r][p] holds global 16B-block (p ^ (r&7)) of row r.
template<bool ADD, bool WBF, bool GUARDN>
__global__ __launch_bounds__(256) void gemm_bt_kern(
    const u16* __restrict__ A, const u16* __restrict__ B,
    float* __restrict__ C, u16* __restrict__ Cbf,
    int M, int N, int K)
{
  __shared__ u16 As[128 * 64];
  __shared__ u16 Bs[128 * 64];
  const int tid  = threadIdx.x;
  const int wave = tid >> 6;
  const int lane = tid & 63;
  const int wr = wave >> 1, wc = wave & 1;
  const int m0 = blockIdx.x * 128;
  const int n0 = blockIdx.y * 128;
  const int lrow = lane >> 3;            // row within 8-row staging chunk
  const int lsw  = (lane & 7) ^ lrow;    // pre-swizzled source 16B-block index

  f32x4 acc[4][4];
#pragma unroll
  for (int i = 0; i < 4; ++i)
#pragma unroll
    for (int j = 0; j < 4; ++j) acc[i][j] = (f32x4){0.f, 0.f, 0.f, 0.f};

  const int arow = wr * 64 + (lane & 15);
  const int brow = wc * 64 + (lane & 15);

  for (int k0 = 0; k0 < K; k0 += 64) {
#pragma unroll
    for (int j = 0; j < 4; ++j) {
      const int chunk = (wave << 2) + j;           // 0..15
      const int r = (chunk << 3) + lrow;           // tile row 0..127
      async16(A + ((long)(m0 + r) * K + k0 + lsw * 8), (char*)As + (chunk << 10));
      async16(B + ((long)(n0 + r) * K + k0 + lsw * 8), (char*)Bs + (chunk << 10));
    }
    asm volatile("s_waitcnt vmcnt(0)" ::: "memory");
    __syncthreads();

#pragma unroll
    for (int kk = 0; kk < 64; kk += 32) {
      const int qb = (kk >> 3) + (lane >> 4);      // logical 16B block (0..7)
      bf16x8 af[4], bfr[4];
#pragma unroll
      for (int i = 0; i < 4; ++i) {
        const int rr = arow + i * 16;
        af[i] = *(const bf16x8*)(As + rr * 64 + ((qb ^ (rr & 7)) << 3));
      }
#pragma unroll
      for (int j = 0; j < 4; ++j) {
        const int rr = brow + j * 16;
        bfr[j] = *(const bf16x8*)(Bs + rr * 64 + ((qb ^ (rr & 7)) << 3));
      }
#pragma unroll
      for (int i = 0; i < 4; ++i)
#pragma unroll
        for (int j = 0; j < 4; ++j)
          acc[i][j] = __builtin_amdgcn_mfma_f32_16x16x32_bf16(af[i], bfr[j], acc[i][j], 0, 0, 0);
    }
    __syncthreads();
  }

  // C/D layout: col = lane&15, row = (lane>>4)*4 + reg
  const int rbase = m0 + wr * 64 + ((lane >> 4) << 2);
  const int cbase = n0 + wc * 64 + (lane & 15);
#pragma unroll
  for (int j = 0; j < 4; ++j) {
    const int col = cbase + j * 16;
    if (GUARDN && col >= N) continue;
#pragma unroll
    for (int i = 0; i < 4; ++i) {
#pragma unroll
      for (int r = 0; r < 4; ++r) {
        const int row = rbase + i * 16 + r;
        const long off = (long)row * N + col;
        float v = acc[i][j][r];
        if (ADD) v += C[off];
        C[off] = v;
        if (WBF) Cbf[off] = f2bf(v);
      }
    }
  }
}

// ---------------------------------------------------------------- causal depthwise conv + SiLU
__global__ void conv_silu_kern(const float* __restrict__ xz, const float* __restrict__ cw,
                               float* __restrict__ xs) {
  int i = blockIdx.x * blockDim.x + threadIdx.x;
  if (i >= MROWS * DINNER) return;
  int c = i % DINNER;
  int t = (i / DINNER) % SEQ;
  int b = i / (DINNER * SEQ);
  const float* w = cw + c * DCONV;
  float a = 0.f;
#pragma unroll
  for (int k = 0; k < DCONV; ++k) {
    int tt = t - (DCONV - 1) + k;
    if (tt >= 0) a += w[k] * xz[(long)(b * SEQ + tt) * (2 * DINNER) + c];
  }
  float s = a / (1.f + __expf(-a));
  xs[i] = a == a ? s * 1.f : s;   // plain silu; keep simple
}

// ---------------------------------------------------------------- x-projection (dt_raw, B, C) + delta
__global__ __launch_bounds__(256) void xproj_kern(
    const float* __restrict__ xs, const float* __restrict__ Wx,
    const float* __restrict__ wdt, const float* __restrict__ bdt,
    float* __restrict__ dlt, float* __restrict__ bc)
{
  __shared__ float sx[DINNER];
  __shared__ float sxp[40];
  const int row = blockIdx.x;
  const int tid = threadIdx.x;
  const float* xr = xs + (long)row * DINNER;
  for (int d = tid; d < DINNER; d += 256) sx[d] = xr[d];
  __syncthreads();
  const int wv = tid >> 6, lane = tid & 63;
  for (int e = wv; e < 2 * DSTATE + 1; e += 4) {
    const float* We = Wx + (long)e * DINNER;
    float p = 0.f;
    for (int d = lane; d < DINNER; d += 64) p += sx[d] * We[d];
#pragma unroll
    for (int off = 32; off; off >>= 1) p += __shfl_xor(p, off, 64);
    if (lane == 0) sxp[e] = p;
  }
  __syncthreads();
  const float dtr = sxp[0];
  for (int d = tid; d < DINNER; d += 256) {
    float v = dtr * wdt[d] + bdt[d];
    float sp = (v > 15.f) ? v : log1pf(__expf(v));
    dlt[(long)row * DINNER + d] = sp;
  }
  if (tid < 2 * DSTATE) bc[(long)row * (2 * DSTATE) + tid] = sxp[1 + tid];
}

// ---------------------------------------------------------------- chunked selective scan + gate
// channels = BATCH*DINNER; per block: 8 channels x 16 chunks of 32 steps (128 thr).
__global__ __launch_bounds__(128) void scan_kern(
    const float* __restrict__ dlt, const float* __restrict__ bc,
    const float* __restrict__ xs, const float* __restrict__ xz,
    const float* __restrict__ alog, const float* __restrict__ dpar,
    u16* __restrict__ ybf)
{
  __shared__ float sh_h[16][8][DSTATE];
  __shared__ float sh_s[16][8];
  const int tid = threadIdx.x;
  const int ch = tid & 7, chunk = tid >> 3;
  const int ch_abs = blockIdx.x * 8 + ch;
  const int b = ch_abs / DINNER, d = ch_abs % DINNER;
  float An[DSTATE];
#pragma unroll
  for (int n = 0; n < DSTATE; ++n) An[n] = -__expf(alog[(long)d * DSTATE + n]);
  const int r0 = b * SEQ + chunk * 32;

  // pass 1: local scan (h_in = 0) + sum of deltas
  float h[DSTATE];
#pragma unroll
  for (int n = 0; n < DSTATE; ++n) h[n] = 0.f;
  float ssum = 0.f;
  for (int s = 0; s < 32; ++s) {
    const int row = r0 + s;
    const float dl = dlt[(long)row * DINNER + d];
    const float xv = xs[(long)row * DINNER + d];
    const float dx = dl * xv;
    const float4* bp = (const float4*)(bc + (long)row * (2 * DSTATE));
    float Bv[DSTATE];
    *(float4*)&Bv[0]  = bp[0]; *(float4*)&Bv[4]  = bp[1];
    *(float4*)&Bv[8]  = bp[2]; *(float4*)&Bv[12] = bp[3];
    ssum += dl;
#pragma unroll
    for (int n = 0; n < DSTATE; ++n) h[n] = __expf(dl * An[n]) * h[n] + dx * Bv[n];
  }
#pragma unroll
  for (int n = 0; n < DSTATE; ++n) sh_h[chunk][ch][n] = h[n];
  sh_s[chunk][ch] = ssum;
  __syncthreads();

  // combine: thread (ch2,n2) scans 16 chunks; sh_h becomes h_in per chunk
  {
    const int n2 = tid & 15, ch2 = tid >> 4;
    const int d2 = (blockIdx.x * 8 + ch2) % DINNER;
    const float A2 = -__expf(alog[(long)d2 * DSTATE + n2]);
    float carry = 0.f;
    for (int c = 0; c < 16; ++c) {
      const float hl = sh_h[c][ch2][n2];
      sh_h[c][ch2][n2] = carry;
      carry = __expf(A2 * sh_s[c][ch2]) * carry + hl;
    }
  }
  __syncthreads();

  // pass 2: real scan with correct h_in, emit gated y
#pragma unroll
  for (int n = 0; n < DSTATE; ++n) h[n] = sh_h[chunk][ch][n];
  const float dp = dpar[d];
  for (int s = 0; s < 32; ++s) {
    const int row = r0 + s;
    const float dl = dlt[(long)row * DINNER + d];
    const float xv = xs[(long)row * DINNER + d];
    const float dx = dl * xv;
    const float4* bp = (const float4*)(bc + (long)row * (2 * DSTATE));
    float Bv[DSTATE], Cv[DSTATE];
    *(float4*)&Bv[0]  = bp[0]; *(float4*)&Bv[4]  = bp[1];
    *(float4*)&Bv[8]  = bp[2]; *(float4*)&Bv[12] = bp[3];
    *(float4*)&Cv[0]  = bp[4]; *(float4*)&Cv[4]  = bp[5];
    *(float4*)&Cv[8]  = bp[6]; *(float4*)&Cv[12] = bp[7];
    float y = 0.f;
#pragma unroll
    for (int n = 0; n < DSTATE; ++n) {
      const float hn = __expf(dl * An[n]) * h[n] + dx * Bv[n];
      h[n] = hn;
      y += Cv[n] * hn;
    }
    y += dp * xv;
    const float zz = xz[(long)row * (2 * DINNER) + DINNER + d];
    const float o = y * (zz / (1.f + __expf(-zz)));
    ybf[(long)row * DINNER + d] = f2bf(o);
  }
}

// ---------------------------------------------------------------- RMSNorm -> bf16
__global__ __launch_bounds__(256) void rmsnorm_kern(const float* __restrict__ x,
                                                    const float* __restrict__ nw,
                                                    u16* __restrict__ xnbf) {
  const int row = blockIdx.x, tid = threadIdx.x;
  const float* xr = x + (long)row * DMODEL;
  float p = 0.f;
#pragma unroll
  for (int k = 0; k < 3; ++k) { float v = xr[tid + k * 256]; p += v * v; }
#pragma unroll
  for (int off = 32; off; off >>= 1) p += __shfl_xor(p, off, 64);
  __shared__ float red[4];
  __shared__ float s_rms;
  const int wv = tid >> 6, lane = tid & 63;
  if (lane == 0) red[wv] = p;
  __syncthreads();
  if (tid == 0) {
    float t = red[0] + red[1] + red[2] + red[3];
    s_rms = rsqrtf(t / (float)DMODEL + 1e-5f);
  }
  __syncthreads();
  const float r = s_rms;
#pragma unroll
  for (int k = 0; k < 3; ++k) {
    const int dd = tid + k * 256;
    xnbf[(long)row * DMODEL + dd] = f2bf(xr[dd] * r * nw[dd]);
  }
}

// ---------------------------------------------------------------- host
extern "C" void kernel_launch(void* const* d_in, const int* in_sizes, int n_in,
                              void* d_out, int out_size, void* d_ws, size_t ws_size,
                              hipStream_t stream)
{
  (void)in_sizes; (void)n_in; (void)out_size; (void)ws_size;
  const int*   idx   = (const int*)  d_in[0];
  const float* emb   = (const float*)d_in[1];
  const float* W_in  = (const float*)d_in[2];
  const float* convw = (const float*)d_in[3];
  const float* W_xp  = (const float*)d_in[4];
  const float* W_dt  = (const float*)d_in[5];
  const float* b_dt  = (const float*)d_in[6];
  const float* a_log = (const float*)d_in[7];
  const float* d_par = (const float*)d_in[8];
  const float* W_out = (const float*)d_in[9];
  const float* normw = (const float*)d_in[10];
  float* out = (float*)d_out;

  char* ws = (char*)d_ws;
  size_t off = 0;
  auto alloc = [&](size_t bytes) -> void* {
    void* p = ws + off;
    off += (bytes + 255) & ~(size_t)255;
    return p;
  };
  u16*   embbf  = (u16*)  alloc((size_t)VPAD * DMODEL * 2);
  u16*   winbf  = (u16*)  alloc((size_t)NLAYER * 2 * DINNER * DMODEL * 2);
  u16*   woutbf = (u16*)  alloc((size_t)NLAYER * DMODEL * DINNER * 2);
  float* xf     = (float*)alloc((size_t)MROWS * DMODEL * 4);
  u16*   xbf    = (u16*)  alloc((size_t)MROWS * DMODEL * 2);
  float* xz     = (float*)alloc((size_t)MROWS * 2 * DINNER * 4);
  float* xs     = (float*)alloc((size_t)MROWS * DINNER * 4);
  float* dlt    = (float*)alloc((size_t)MROWS * DINNER * 4);
  float* bc     = (float*)alloc((size_t)MROWS * 2 * DSTATE * 4);
  u16*   ybf    = (u16*)  alloc((size_t)MROWS * DINNER * 2);
  u16*   xnbf   = (u16*)  alloc((size_t)MROWS * DMODEL * 2);

  cvt_pad_kern<<<4096, 256, 0, stream>>>(emb, embbf, VV * DMODEL / 4, VPAD * DMODEL / 4);
  cvt_kern<<<4096, 256, 0, stream>>>(W_in, winbf, NLAYER * 2 * DINNER * DMODEL / 4);
  cvt_kern<<<2048, 256, 0, stream>>>(W_out, woutbf, NLAYER * DMODEL * DINNER / 4);
  embed_kern<<<(MROWS * DMODEL / 4 + 255) / 256, 256, 0, stream>>>(idx, emb, xf, xbf);

  for (int l = 0; l < NLAYER; ++l) {
    gemm_bt_kern<false, false, false><<<dim3(MROWS / 128, 2 * DINNER / 128), 256, 0, stream>>>(
        xbf, winbf + (size_t)l * 2 * DINNER * DMODEL, xz, nullptr, MROWS, 2 * DINNER, DMODEL);
    conv_silu_kern<<<MROWS * DINNER / 256, 256, 0, stream>>>(
        xz, convw + (size_t)l * DINNER * DCONV, xs);
    xproj_kern<<<MROWS, 256, 0, stream>>>(
        xs, W_xp + (size_t)l * (2 * DSTATE + 1) * DINNER,
        W_dt + (size_t)l * DINNER, b_dt + (size_t)l * DINNER, dlt, bc);
    scan_kern<<<BATCH * DINNER / 8, 128, 0, stream>>>(
        dlt, bc, xs, xz, a_log + (size_t)l * DINNER * DSTATE, d_par + (size_t)l * DINNER, ybf);
    gemm_bt_kern<true, true, false><<<dim3(MROWS / 128, DMODEL / 128), 256, 0, stream>>>(
        ybf, woutbf + (size_t)l * DMODEL * DINNER, xf, xbf, MROWS, DMODEL, DINNER);
  }
  rmsnorm_kern<<<MROWS, 256, 0, stream>>>(xf, normw, xnbf);
  gemm_bt_kern<false, false, true><<<dim3(MROWS / 128, (VV + 127) / 128), 256, 0, stream>>>(
      xnbf, embbf, out, nullptr, MROWS, VV, DMODEL);
}

// Round 2
// 942.736 us; speedup vs baseline: 1.1345x; 1.1345x over previous
//
#include <hip/hip_runtime.h>
#include <cstdint>

#define VV     50257
#define VPAD   50304
#define DMODEL 768
#define NLAYER 4
#define DINNER 1536
#define DSTATE 16
#define DCONV  4
#define BATCH  2
#define SEQ    512
#define MROWS  (BATCH*SEQ)   // 1024

typedef unsigned short u16;
typedef __attribute__((ext_vector_type(8))) short bf16x8;
typedef __attribute__((ext_vector_type(4))) float f32x4;

__device__ __forceinline__ u16 f2bf(float f) {
  unsigned u = __float_as_uint(f);
  u += 0x7fffu + ((u >> 16) & 1u);
  return (u16)(u >> 16);
}

__device__ __forceinline__ void async16(const void* g, void* l) {
  auto gp = reinterpret_cast<const __attribute__((address_space(1))) unsigned int*>(
      reinterpret_cast<uintptr_t>(g));
  auto lp = reinterpret_cast<__attribute__((address_space(3))) unsigned int*>(
      reinterpret_cast<uintptr_t>(l));
  __builtin_amdgcn_global_load_lds(gp, lp, 16, 0, 0);
}

// ---------------------------------------------------------------- conversions
__global__ void cvt_kern(const float* __restrict__ src, u16* __restrict__ dst, int n4) {
  int i = blockIdx.x * blockDim.x + threadIdx.x;
  int stride = gridDim.x * blockDim.x;
  for (; i < n4; i += stride) {
    float4 v = *(const float4*)(src + (long)i * 4);
    ushort4 o; o.x = f2bf(v.x); o.y = f2bf(v.y); o.z = f2bf(v.z); o.w = f2bf(v.w);
    *(ushort4*)(dst + (long)i * 4) = o;
  }
}

__global__ void cvt_pad_kern(const float* __restrict__ src, u16* __restrict__ dst,
                             int nsrc4, int ntot4) {
  int i = blockIdx.x * blockDim.x + threadIdx.x;
  int stride = gridDim.x * blockDim.x;
  for (; i < ntot4; i += stride) {
    ushort4 o;
    if (i < nsrc4) {
      float4 v = *(const float4*)(src + (long)i * 4);
      o.x = f2bf(v.x); o.y = f2bf(v.y); o.z = f2bf(v.z); o.w = f2bf(v.w);
    } else {
      o.x = 0; o.y = 0; o.z = 0; o.w = 0;
    }
    *(ushort4*)(dst + (long)i * 4) = o;
  }
}

// ---------------------------------------------------------------- embedding
__global__ void embed_kern(const int* __restrict__ idx, const float* __restrict__ emb,
                           float* __restrict__ x, u16* __restrict__ xbf) {
  int i4 = blockIdx.x * blockDim.x + threadIdx.x;
  if (i4 >= MROWS * (DMODEL / 4)) return;
  int r = i4 / (DMODEL / 4);
  int c = (i4 % (DMODEL / 4)) * 4;
  int id = idx[r];
  float4 v = *(const float4*)(emb + (long)id * DMODEL + c);
  *(float4*)(x + (long)r * DMODEL + c) = v;
  ushort4 o; o.x = f2bf(v.x); o.y = f2bf(v.y); o.z = f2bf(v.z); o.w = f2bf(v.w);
  *(ushort4*)(xbf + (long)r * DMODEL + c) = o;
}

// ---------------------------------------------------------------- bf16 BT-GEMM
// C[m,n] = sum_k A[m,k]*B[n,k]. 128x128 tile, K-step 64, 4 waves, 16x16x32 MFMA.
// XSWZ: 1-D grid of 8*nt blocks; remap so each XCD owns contiguous N-panels
// (all 8 M-tiles co-resident in its L2). Requires M == 1024.
// blockIdx.z = split-K slice: A col offset z*K, C offset z*M*N.
template<bool ADD, bool WBF, bool GUARDN, bool XSWZ>
__global__ __launch_bounds__(256) void gemm_bt_kern(
    const u16* __restrict__ A, const u16* __restrict__ B,
    float* __restrict__ C, u16* __restrict__ Cbf,
    int M, int N, int K, int lda, int ldb)
{
  __shared__ u16 As[128 * 64];
  __shared__ u16 Bs[128 * 64];
  int bx, by;
  if (XSWZ) {
    const int nt = gridDim.x >> 3;
    const int t = (blockIdx.x & 7) * nt + (blockIdx.x >> 3);
    bx = t & 7; by = t >> 3;
  } else { bx = blockIdx.x; by = blockIdx.y; }
  const int koff = blockIdx.z * K;
  const long coff = (long)blockIdx.z * M * N;

  const int tid  = threadIdx.x;
  const int wave = tid >> 6;
  const int lane = tid & 63;
  const int wr = wave >> 1, wc = wave & 1;
  const int m0 = bx * 128;
  const int n0 = by * 128;
  const int lrow = lane >> 3;
  const int lsw  = (lane & 7) ^ lrow;

  f32x4 acc[4][4];
#pragma unroll
  for (int i = 0; i < 4; ++i)
#pragma unroll
    for (int j = 0; j < 4; ++j) acc[i][j] = (f32x4){0.f, 0.f, 0.f, 0.f};

  const int arow = wr * 64 + (lane & 15);
  const int brow = wc * 64 + (lane & 15);

  for (int k0 = 0; k0 < K; k0 += 64) {
#pragma unroll
    for (int j = 0; j < 4; ++j) {
      const int chunk = (wave << 2) + j;
      const int r = (chunk << 3) + lrow;
      async16(A + ((long)(m0 + r) * lda + koff + k0 + lsw * 8), (char*)As + (chunk << 10));
      async16(B + ((long)(n0 + r) * ldb + koff + k0 + lsw * 8), (char*)Bs + (chunk << 10));
    }
    asm volatile("s_waitcnt vmcnt(0)" ::: "memory");
    __syncthreads();

#pragma unroll
    for (int kk = 0; kk < 64; kk += 32) {
      const int qb = (kk >> 3) + (lane >> 4);
      bf16x8 af[4], bfr[4];
#pragma unroll
      for (int i = 0; i < 4; ++i) {
        const int rr = arow + i * 16;
        af[i] = *(const bf16x8*)(As + rr * 64 + ((qb ^ (rr & 7)) << 3));
      }
#pragma unroll
      for (int j = 0; j < 4; ++j) {
        const int rr = brow + j * 16;
        bfr[j] = *(const bf16x8*)(Bs + rr * 64 + ((qb ^ (rr & 7)) << 3));
      }
#pragma unroll
      for (int i = 0; i < 4; ++i)
#pragma unroll
        for (int j = 0; j < 4; ++j)
          acc[i][j] = __builtin_amdgcn_mfma_f32_16x16x32_bf16(af[i], bfr[j], acc[i][j], 0, 0, 0);
    }
    __syncthreads();
  }

  const int rbase = m0 + wr * 64 + ((lane >> 4) << 2);
  const int cbase = n0 + wc * 64 + (lane & 15);
#pragma unroll
  for (int j = 0; j < 4; ++j) {
    const int col = cbase + j * 16;
    if (GUARDN && col >= N) continue;
#pragma unroll
    for (int i = 0; i < 4; ++i) {
#pragma unroll
      for (int r = 0; r < 4; ++r) {
        const int row = rbase + i * 16 + r;
        const long off = coff + (long)row * N + col;
        float v = acc[i][j][r];
        if (ADD) v += C[off];
        C[off] = v;
        if (WBF) Cbf[off] = f2bf(v);
      }
    }
  }
}

// ---------------------------------------------------------------- split-K reduce + residual + bf16
__global__ __launch_bounds__(256) void redout_kern(const float* __restrict__ part,
                                                   float* __restrict__ xf,
                                                   u16* __restrict__ xbf) {
  const int i = blockIdx.x * blockDim.x + threadIdx.x;   // over M*D/4
  if (i >= MROWS * DMODEL / 4) return;
  const int stride4 = MROWS * DMODEL / 4;
  float4 s = ((const float4*)part)[i];
  float4 p1 = ((const float4*)part)[i + stride4];
  float4 p2 = ((const float4*)part)[i + 2 * stride4];
  float4 p3 = ((const float4*)part)[i + 3 * stride4];
  float4 x = ((const float4*)xf)[i];
  s.x += p1.x + p2.x + p3.x + x.x;
  s.y += p1.y + p2.y + p3.y + x.y;
  s.z += p1.z + p2.z + p3.z + x.z;
  s.w += p1.w + p2.w + p3.w + x.w;
  ((float4*)xf)[i] = s;
  ushort4 o; o.x = f2bf(s.x); o.y = f2bf(s.y); o.z = f2bf(s.z); o.w = f2bf(s.w);
  ((ushort4*)xbf)[i] = o;
}

// ---------------------------------------------------------------- fused conv+SiLU+xproj+delta
__global__ __launch_bounds__(256) void convxproj_kern(
    const float* __restrict__ xz, const float* __restrict__ cw,
    const float* __restrict__ Wx, const float* __restrict__ wdt,
    const float* __restrict__ bdt,
    float* __restrict__ xs, float* __restrict__ dlt, float* __restrict__ bc)
{
  __shared__ float sx[DINNER];
  __shared__ float sxp[40];
  const int row = blockIdx.x;       // b*SEQ + t
  const int t = row & (SEQ - 1);
  const int tid = threadIdx.x;

  for (int c = tid; c < DINNER; c += 256) {
    const float* w = cw + c * DCONV;
    float a = 0.f;
#pragma unroll
    for (int k = 0; k < DCONV; ++k) {
      const int tt = t - (DCONV - 1) + k;
      if (tt >= 0) a += w[k] * xz[(long)(row - (DCONV - 1) + k) * (2 * DINNER) + c];
    }
    const float s = a / (1.f + __expf(-a));
    sx[c] = s;
    xs[(long)row * DINNER + c] = s;
  }
  __syncthreads();

  const int wv = tid >> 6, lane = tid & 63;
  for (int e = wv; e < 2 * DSTATE + 1; e += 4) {
    const float* We = Wx + (long)e * DINNER;
    float p = 0.f;
    for (int d = lane; d < DINNER; d += 64) p += sx[d] * We[d];
#pragma unroll
    for (int off = 32; off; off >>= 1) p += __shfl_xor(p, off, 64);
    if (lane == 0) sxp[e] = p;
  }
  __syncthreads();
  const float dtr = sxp[0];
  for (int d = tid; d < DINNER; d += 256) {
    float v = dtr * wdt[d] + bdt[d];
    float sp = (v > 15.f) ? v : log1pf(__expf(v));
    dlt[(long)row * DINNER + d] = sp;
  }
  if (tid < 2 * DSTATE) bc[(long)row * (2 * DSTATE) + tid] = sxp[1 + tid];
}

// ---------------------------------------------------------------- chunked selective scan + gate
__global__ __launch_bounds__(128) void scan_kern(
    const float* __restrict__ dlt, const float* __restrict__ bc,
    const float* __restrict__ xs, const float* __restrict__ xz,
    const float* __restrict__ alog, const float* __restrict__ dpar,
    u16* __restrict__ ybf)
{
  __shared__ float sh_h[16][8][DSTATE];
  __shared__ float sh_s[16][8];
  const int tid = threadIdx.x;
  const int ch = tid & 7, chunk = tid >> 3;
  const int ch_abs = blockIdx.x * 8 + ch;
  const int b = ch_abs / DINNER, d = ch_abs % DINNER;
  float An[DSTATE];
#pragma unroll
  for (int n = 0; n < DSTATE; ++n) An[n] = -__expf(alog[(long)d * DSTATE + n]);
  const int r0 = b * SEQ + chunk * 32;

  float h[DSTATE];
#pragma unroll
  for (int n = 0; n < DSTATE; ++n) h[n] = 0.f;
  float ssum = 0.f;
  for (int s = 0; s < 32; ++s) {
    const int row = r0 + s;
    const float dl = dlt[(long)row * DINNER + d];
    const float xv = xs[(long)row * DINNER + d];
    const float dx = dl * xv;
    const float4* bp = (const float4*)(bc + (long)row * (2 * DSTATE));
    float Bv[DSTATE];
    *(float4*)&Bv[0]  = bp[0]; *(float4*)&Bv[4]  = bp[1];
    *(float4*)&Bv[8]  = bp[2]; *(float4*)&Bv[12] = bp[3];
    ssum += dl;
#pragma unroll
    for (int n = 0; n < DSTATE; ++n) h[n] = __expf(dl * An[n]) * h[n] + dx * Bv[n];
  }
#pragma unroll
  for (int n = 0; n < DSTATE; ++n) sh_h[chunk][ch][n] = h[n];
  sh_s[chunk][ch] = ssum;
  __syncthreads();

  {
    const int n2 = tid & 15, ch2 = tid >> 4;
    const int d2 = (blockIdx.x * 8 + ch2) % DINNER;
    const float A2 = -__expf(alog[(long)d2 * DSTATE + n2]);
    float carry = 0.f;
    for (int c = 0; c < 16; ++c) {
      const float hl = sh_h[c][ch2][n2];
      sh_h[c][ch2][n2] = carry;
      carry = __expf(A2 * sh_s[c][ch2]) * carry + hl;
    }
  }
  __syncthreads();

#pragma unroll
  for (int n = 0; n < DSTATE; ++n) h[n] = sh_h[chunk][ch][n];
  const float dp = dpar[d];
  for (int s = 0; s < 32; ++s) {
    const int row = r0 + s;
    const float dl = dlt[(long)row * DINNER + d];
    const float xv = xs[(long)row * DINNER + d];
    const float dx = dl * xv;
    const float4* bp = (const float4*)(bc + (long)row * (2 * DSTATE));
    float Bv[DSTATE], Cv[DSTATE];
    *(float4*)&Bv[0]  = bp[0]; *(float4*)&Bv[4]  = bp[1];
    *(float4*)&Bv[8]  = bp[2]; *(float4*)&Bv[12] = bp[3];
    *(float4*)&Cv[0]  = bp[4]; *(float4*)&Cv[4]  = bp[5];
    *(float4*)&Cv[8]  = bp[6]; *(float4*)&Cv[12] = bp[7];
    float y = 0.f;
#pragma unroll
    for (int n = 0; n < DSTATE; ++n) {
      const float hn = __expf(dl * An[n]) * h[n] + dx * Bv[n];
      h[n] = hn;
      y += Cv[n] * hn;
    }
    y += dp * xv;
    const float zz = xz[(long)row * (2 * DINNER) + DINNER + d];
    const float o = y * (zz / (1.f + __expf(-zz)));
    ybf[(long)row * DINNER + d] = f2bf(o);
  }
}

// ---------------------------------------------------------------- RMSNorm -> bf16
__global__ __launch_bounds__(256) void rmsnorm_kern(const float* __restrict__ x,
                                                    const float* __restrict__ nw,
                                                    u16* __restrict__ xnbf) {
  const int row = blockIdx.x, tid = threadIdx.x;
  const float* xr = x + (long)row * DMODEL;
  float p = 0.f;
#pragma unroll
  for (int k = 0; k < 3; ++k) { float v = xr[tid + k * 256]; p += v * v; }
#pragma unroll
  for (int off = 32; off; off >>= 1) p += __shfl_xor(p, off, 64);
  __shared__ float red[4];
  __shared__ float s_rms;
  const int wv = tid >> 6, lane = tid & 63;
  if (lane == 0) red[wv] = p;
  __syncthreads();
  if (tid == 0) {
    float tsum = red[0] + red[1] + red[2] + red[3];
    s_rms = rsqrtf(tsum / (float)DMODEL + 1e-5f);
  }
  __syncthreads();
  const float r = s_rms;
#pragma unroll
  for (int k = 0; k < 3; ++k) {
    const int dd = tid + k * 256;
    xnbf[(long)row * DMODEL + dd] = f2bf(xr[dd] * r * nw[dd]);
  }
}

// ---------------------------------------------------------------- host
extern "C" void kernel_launch(void* const* d_in, const int* in_sizes, int n_in,
                              void* d_out, int out_size, void* d_ws, size_t ws_size,
                              hipStream_t stream)
{
  (void)in_sizes; (void)n_in; (void)out_size; (void)ws_size;
  const int*   idx   = (const int*)  d_in[0];
  const float* emb   = (const float*)d_in[1];
  const float* W_in  = (const float*)d_in[2];
  const float* convw = (const float*)d_in[3];
  const float* W_xp  = (const float*)d_in[4];
  const float* W_dt  = (const float*)d_in[5];
  const float* b_dt  = (const float*)d_in[6];
  const float* a_log = (const float*)d_in[7];
  const float* d_par = (const float*)d_in[8];
  const float* W_out = (const float*)d_in[9];
  const float* normw = (const float*)d_in[10];
  float* out = (float*)d_out;

  char* ws = (char*)d_ws;
  size_t off = 0;
  auto alloc = [&](size_t bytes) -> void* {
    void* p = ws + off;
    off += (bytes + 255) & ~(size_t)255;
    return p;
  };
  u16*   embbf  = (u16*)  alloc((size_t)VPAD * DMODEL * 2);
  u16*   winbf  = (u16*)  alloc((size_t)NLAYER * 2 * DINNER * DMODEL * 2);
  u16*   woutbf = (u16*)  alloc((size_t)NLAYER * DMODEL * DINNER * 2);
  float* xf     = (float*)alloc((size_t)MROWS * DMODEL * 4);
  u16*   xbf    = (u16*)  alloc((size_t)MROWS * DMODEL * 2);
  float* xz     = (float*)alloc((size_t)MROWS * 2 * DINNER * 4);
  float* xs     = (float*)alloc((size_t)MROWS * DINNER * 4);
  float* dlt    = (float*)alloc((size_t)MROWS * DINNER * 4);
  float* bc     = (float*)alloc((size_t)MROWS * 2 * DSTATE * 4);
  u16*   ybf    = (u16*)  alloc((size_t)MROWS * DINNER * 2);
  u16*   xnbf   = (u16*)  alloc((size_t)MROWS * DMODEL * 2);
  float* part   = (float*)alloc((size_t)4 * MROWS * DMODEL * 4);

  cvt_pad_kern<<<4096, 256, 0, stream>>>(emb, embbf, VV * DMODEL / 4, VPAD * DMODEL / 4);
  cvt_kern<<<4096, 256, 0, stream>>>(W_in, winbf, NLAYER * 2 * DINNER * DMODEL / 4);
  cvt_kern<<<2048, 256, 0, stream>>>(W_out, woutbf, NLAYER * DMODEL * DINNER / 4);
  embed_kern<<<(MROWS * DMODEL / 4 + 255) / 256, 256, 0, stream>>>(idx, emb, xf, xbf);

  for (int l = 0; l < NLAYER; ++l) {
    // xz = x @ W_in^T   (M=1024, N=3072, K=768), XCD-colocated
    gemm_bt_kern<false, false, false, true><<<8 * (2 * DINNER / 128), 256, 0, stream>>>(
        xbf, winbf + (size_t)l * 2 * DINNER * DMODEL, xz, nullptr,
        MROWS, 2 * DINNER, DMODEL, DMODEL, DMODEL);
    convxproj_kern<<<MROWS, 256, 0, stream>>>(
        xz, convw + (size_t)l * DINNER * DCONV,
        W_xp + (size_t)l * (2 * DSTATE + 1) * DINNER,
        W_dt + (size_t)l * DINNER, b_dt + (size_t)l * DINNER, xs, dlt, bc);
    scan_kern<<<BATCH * DINNER / 8, 128, 0, stream>>>(
        dlt, bc, xs, xz, a_log + (size_t)l * DINNER * DSTATE, d_par + (size_t)l * DINNER, ybf);
    // out-proj split-K x4: partials (M=1024, N=768, Kseg=384)
    gemm_bt_kern<false, false, false, true><<<dim3(8 * (DMODEL / 128), 1, 4), 256, 0, stream>>>(
        ybf, woutbf + (size_t)l * DMODEL * DINNER, part, nullptr,
        MROWS, DMODEL, DINNER / 4, DINNER, DINNER);
    redout_kern<<<MROWS * DMODEL / 4 / 256, 256, 0, stream>>>(part, xf, xbf);
  }
  rmsnorm_kern<<<MROWS, 256, 0, stream>>>(xf, normw, xnbf);
  // logits = xn @ emb^T  (M=1024, N=50257, K=768), XCD-colocated
  gemm_bt_kern<false, false, true, true><<<8 * (VPAD / 128), 256, 0, stream>>>(
      xnbf, embbf, out, nullptr, MROWS, VV, DMODEL, DMODEL, DMODEL);
}

// Round 3
// 918.836 us; speedup vs baseline: 1.1640x; 1.0260x over previous
//
#include <hip/hip_runtime.h>
#include <cstdint>

#define VV     50257
#define VPAD   50304
#define DMODEL 768
#define NLAYER 4
#define DINNER 1536
#define DSTATE 16
#define DCONV  4
#define BATCH  2
#define SEQ    512
#define MROWS  (BATCH*SEQ)   // 1024

typedef unsigned short u16;
typedef __attribute__((ext_vector_type(8))) short bf16x8;
typedef __attribute__((ext_vector_type(4))) float f32x4;

__device__ __forceinline__ u16 f2bf(float f) {
  unsigned u = __float_as_uint(f);
  u += 0x7fffu + ((u >> 16) & 1u);
  return (u16)(u >> 16);
}

__device__ __forceinline__ void async16(const void* g, void* l) {
  auto gp = reinterpret_cast<const __attribute__((address_space(1))) unsigned int*>(
      reinterpret_cast<uintptr_t>(g));
  auto lp = reinterpret_cast<__attribute__((address_space(3))) unsigned int*>(
      reinterpret_cast<uintptr_t>(l));
  __builtin_amdgcn_global_load_lds(gp, lp, 16, 0, 0);
}

// ---------------------------------------------------------------- fused prep:
// emb->bf16(padded) | W_in->bf16 | W_out->bf16 | embed gather (fp32 + bf16)
__global__ void prep_kern(const float* __restrict__ emb, const float* __restrict__ W_in,
                          const float* __restrict__ W_out, const int* __restrict__ idx,
                          u16* __restrict__ embbf, u16* __restrict__ winbf,
                          u16* __restrict__ woutbf, float* __restrict__ xf,
                          u16* __restrict__ xbf) {
  const int E4  = VPAD * DMODEL / 4;                    // padded emb chunks
  const int W14 = NLAYER * 2 * DINNER * DMODEL / 4;
  const int W24 = NLAYER * DMODEL * DINNER / 4;
  const int X4  = MROWS * DMODEL / 4;
  const int TOT = E4 + W14 + W24 + X4;
  int i = blockIdx.x * blockDim.x + threadIdx.x;
  const int stride = gridDim.x * blockDim.x;
  for (; i < TOT; i += stride) {
    if (i < E4) {
      ushort4 o;
      if (i < VV * DMODEL / 4) {
        float4 v = *(const float4*)(emb + (long)i * 4);
        o.x = f2bf(v.x); o.y = f2bf(v.y); o.z = f2bf(v.z); o.w = f2bf(v.w);
      } else { o.x = 0; o.y = 0; o.z = 0; o.w = 0; }
      *(ushort4*)(embbf + (long)i * 4) = o;
    } else if (i < E4 + W14) {
      const int j = i - E4;
      float4 v = *(const float4*)(W_in + (long)j * 4);
      ushort4 o; o.x = f2bf(v.x); o.y = f2bf(v.y); o.z = f2bf(v.z); o.w = f2bf(v.w);
      *(ushort4*)(winbf + (long)j * 4) = o;
    } else if (i < E4 + W14 + W24) {
      const int j = i - E4 - W14;
      float4 v = *(const float4*)(W_out + (long)j * 4);
      ushort4 o; o.x = f2bf(v.x); o.y = f2bf(v.y); o.z = f2bf(v.z); o.w = f2bf(v.w);
      *(ushort4*)(woutbf + (long)j * 4) = o;
    } else {
      const int j = i - E4 - W14 - W24;                 // over MROWS*DMODEL/4
      const int r = j / (DMODEL / 4);
      const int c = (j % (DMODEL / 4)) * 4;
      const int id = idx[r];
      float4 v = *(const float4*)(emb + (long)id * DMODEL + c);
      *(float4*)(xf + (long)r * DMODEL + c) = v;
      ushort4 o; o.x = f2bf(v.x); o.y = f2bf(v.y); o.z = f2bf(v.z); o.w = f2bf(v.w);
      *(ushort4*)(xbf + (long)r * DMODEL + c) = o;
    }
  }
}

// ---------------------------------------------------------------- bf16 BT-GEMM, ring-3 counted-vmcnt
// C[m,n] = sum_k A[m,k]*B[n,k]. 128x128 tile, BK=32, 4 waves, 16x16x32 MFMA.
// LDS ring of 3 K-tiles; stage tile t+2 at iter t; s_waitcnt vmcnt(8) (counted,
// never 0 in main loop); raw s_barrier (no vmcnt(0) drain).
// Swizzle: 4 x 16B blocks/row; stored block = global_blk ^ ((row>>1)&3) -> 2-way banks (free).
template<bool GUARDN, bool XSWZ>
__global__ __launch_bounds__(256) void gemm3_kern(
    const u16* __restrict__ A, const u16* __restrict__ B,
    float* __restrict__ C, int M, int N, int K, int lda, int ldb)
{
  __shared__ u16 As[3][128 * 32];
  __shared__ u16 Bs[3][128 * 32];
  int bx, by;
  if (XSWZ) {
    const int nt = gridDim.x >> 3;
    const int t = (blockIdx.x & 7) * nt + (blockIdx.x >> 3);
    bx = t & 7; by = t >> 3;
  } else { bx = blockIdx.x; by = blockIdx.y; }
  const int koff = blockIdx.z * K;
  const long coff = (long)blockIdx.z * M * N;

  const int tid  = threadIdx.x;
  const int wave = tid >> 6;
  const int lane = tid & 63;
  const int wr = wave >> 1, wc = wave & 1;
  const int m0 = bx * 128;
  const int n0 = by * 128;

  // staging: wave w covers tile rows [w*32, w*32+32) of A and of B; 2 instrs each.
  const int srow = wave * 32 + (lane >> 2);                 // + j*16
  const int sblk = ((lane & 3) ^ ((lane >> 3) & 3)) * 8;    // pre-swizzled global block

  f32x4 acc[4][4];
#pragma unroll
  for (int i = 0; i < 4; ++i)
#pragma unroll
    for (int j = 0; j < 4; ++j) acc[i][j] = (f32x4){0.f, 0.f, 0.f, 0.f};

  const int arow = wr * 64 + (lane & 15);
  const int brow = wc * 64 + (lane & 15);
  const int sa   = (((lane >> 4) ^ ((lane >> 1) & 3)) << 3);  // read block offset (u16)

  const int KT = K / 32;
  auto stage = [&](int kt) {
    const int slot = kt % 3;
    const long kcol = (long)koff + kt * 32;
#pragma unroll
    for (int j = 0; j < 2; ++j) {
      async16(A + (long)(m0 + srow + j * 16) * lda + kcol + sblk,
              (char*)(As[slot]) + (wave * 32 + j * 16) * 64);
      async16(B + (long)(n0 + srow + j * 16) * ldb + kcol + sblk,
              (char*)(Bs[slot]) + (wave * 32 + j * 16) * 64);
    }
  };

  stage(0);
  stage(1);
  for (int t = 0; t < KT; ++t) {
    if (t + 2 < KT) {
      stage(t + 2);
      asm volatile("s_waitcnt vmcnt(8)" ::: "memory");
    } else if (t + 2 == KT) {
      asm volatile("s_waitcnt vmcnt(4)" ::: "memory");
    } else {
      asm volatile("s_waitcnt vmcnt(0)" ::: "memory");
    }
    __builtin_amdgcn_s_barrier();
    asm volatile("" ::: "memory");

    const int slot = t % 3;
    const u16* as = As[slot];
    const u16* bs = Bs[slot];
    bf16x8 af[4], bv[4];
#pragma unroll
    for (int i = 0; i < 4; ++i) af[i] = *(const bf16x8*)(as + (arow + 16 * i) * 32 + sa);
#pragma unroll
    for (int j = 0; j < 4; ++j) bv[j] = *(const bf16x8*)(bs + (brow + 16 * j) * 32 + sa);

    __builtin_amdgcn_s_setprio(1);
#pragma unroll
    for (int i = 0; i < 4; ++i)
#pragma unroll
      for (int j = 0; j < 4; ++j)
        acc[i][j] = __builtin_amdgcn_mfma_f32_16x16x32_bf16(af[i], bv[j], acc[i][j], 0, 0, 0);
    __builtin_amdgcn_s_setprio(0);

    asm volatile("" ::: "memory");
    __builtin_amdgcn_s_barrier();
    asm volatile("" ::: "memory");
  }

  // C/D layout: col = lane&15, row = (lane>>4)*4 + reg
  const int rbase = m0 + wr * 64 + ((lane >> 4) << 2);
  const int cbase = n0 + wc * 64 + (lane & 15);
#pragma unroll
  for (int j = 0; j < 4; ++j) {
    const int col = cbase + j * 16;
    if (GUARDN && col >= N) continue;
#pragma unroll
    for (int i = 0; i < 4; ++i) {
#pragma unroll
      for (int r = 0; r < 4; ++r) {
        const int row = rbase + i * 16 + r;
        C[coff + (long)row * N + col] = acc[i][j][r];
      }
    }
  }
}

// ---------------------------------------------------------------- split-K reduce + residual + bf16
__global__ __launch_bounds__(256) void redout_kern(const float* __restrict__ part,
                                                   float* __restrict__ xf,
                                                   u16* __restrict__ xbf) {
  const int i = blockIdx.x * blockDim.x + threadIdx.x;
  if (i >= MROWS * DMODEL / 4) return;
  const int stride4 = MROWS * DMODEL / 4;
  float4 s = ((const float4*)part)[i];
  float4 p1 = ((const float4*)part)[i + stride4];
  float4 p2 = ((const float4*)part)[i + 2 * stride4];
  float4 p3 = ((const float4*)part)[i + 3 * stride4];
  float4 x = ((const float4*)xf)[i];
  s.x += p1.x + p2.x + p3.x + x.x;
  s.y += p1.y + p2.y + p3.y + x.y;
  s.z += p1.z + p2.z + p3.z + x.z;
  s.w += p1.w + p2.w + p3.w + x.w;
  ((float4*)xf)[i] = s;
  ushort4 o; o.x = f2bf(s.x); o.y = f2bf(s.y); o.z = f2bf(s.z); o.w = f2bf(s.w);
  ((ushort4*)xbf)[i] = o;
}

// ---------------------------------------------------------------- fused conv+SiLU+xproj+delta
__global__ __launch_bounds__(256) void convxproj_kern(
    const float* __restrict__ xz, const float* __restrict__ cw,
    const float* __restrict__ Wx, const float* __restrict__ wdt,
    const float* __restrict__ bdt,
    float* __restrict__ xs, float* __restrict__ dlt, float* __restrict__ bc)
{
  __shared__ float sx[DINNER];
  __shared__ float sxp[40];
  const int row = blockIdx.x;       // b*SEQ + t
  const int t = row & (SEQ - 1);
  const int tid = threadIdx.x;

  for (int c = tid; c < DINNER; c += 256) {
    const float* w = cw + c * DCONV;
    float a = 0.f;
#pragma unroll
    for (int k = 0; k < DCONV; ++k) {
      const int tt = t - (DCONV - 1) + k;
      if (tt >= 0) a += w[k] * xz[(long)(row - (DCONV - 1) + k) * (2 * DINNER) + c];
    }
    const float s = a / (1.f + __expf(-a));
    sx[c] = s;
    xs[(long)row * DINNER + c] = s;
  }
  __syncthreads();

  const int wv = tid >> 6, lane = tid & 63;
  for (int e = wv; e < 2 * DSTATE + 1; e += 4) {
    const float* We = Wx + (long)e * DINNER;
    float p = 0.f;
    for (int d = lane; d < DINNER; d += 64) p += sx[d] * We[d];
#pragma unroll
    for (int off = 32; off; off >>= 1) p += __shfl_xor(p, off, 64);
    if (lane == 0) sxp[e] = p;
  }
  __syncthreads();
  const float dtr = sxp[0];
  for (int d = tid; d < DINNER; d += 256) {
    float v = dtr * wdt[d] + bdt[d];
    float sp = (v > 15.f) ? v : log1pf(__expf(v));
    dlt[(long)row * DINNER + d] = sp;
  }
  if (tid < 2 * DSTATE) bc[(long)row * (2 * DSTATE) + tid] = sxp[1 + tid];
}

// ---------------------------------------------------------------- chunked selective scan + gate
__global__ __launch_bounds__(128) void scan_kern(
    const float* __restrict__ dlt, const float* __restrict__ bc,
    const float* __restrict__ xs, const float* __restrict__ xz,
    const float* __restrict__ alog, const float* __restrict__ dpar,
    u16* __restrict__ ybf)
{
  __shared__ float sh_h[16][8][DSTATE];
  __shared__ float sh_s[16][8];
  const int tid = threadIdx.x;
  const int ch = tid & 7, chunk = tid >> 3;
  const int ch_abs = blockIdx.x * 8 + ch;
  const int b = ch_abs / DINNER, d = ch_abs % DINNER;
  float An[DSTATE];
#pragma unroll
  for (int n = 0; n < DSTATE; ++n) An[n] = -__expf(alog[(long)d * DSTATE + n]);
  const int r0 = b * SEQ + chunk * 32;

  float h[DSTATE];
#pragma unroll
  for (int n = 0; n < DSTATE; ++n) h[n] = 0.f;
  float ssum = 0.f;
  for (int s = 0; s < 32; ++s) {
    const int row = r0 + s;
    const float dl = dlt[(long)row * DINNER + d];
    const float xv = xs[(long)row * DINNER + d];
    const float dx = dl * xv;
    const float4* bp = (const float4*)(bc + (long)row * (2 * DSTATE));
    float Bv[DSTATE];
    *(float4*)&Bv[0]  = bp[0]; *(float4*)&Bv[4]  = bp[1];
    *(float4*)&Bv[8]  = bp[2]; *(float4*)&Bv[12] = bp[3];
    ssum += dl;
#pragma unroll
    for (int n = 0; n < DSTATE; ++n) h[n] = __expf(dl * An[n]) * h[n] + dx * Bv[n];
  }
#pragma unroll
  for (int n = 0; n < DSTATE; ++n) sh_h[chunk][ch][n] = h[n];
  sh_s[chunk][ch] = ssum;
  __syncthreads();

  {
    const int n2 = tid & 15, ch2 = tid >> 4;
    const int d2 = (blockIdx.x * 8 + ch2) % DINNER;
    const float A2 = -__expf(alog[(long)d2 * DSTATE + n2]);
    float carry = 0.f;
    for (int c = 0; c < 16; ++c) {
      const float hl = sh_h[c][ch2][n2];
      sh_h[c][ch2][n2] = carry;
      carry = __expf(A2 * sh_s[c][ch2]) * carry + hl;
    }
  }
  __syncthreads();

#pragma unroll
  for (int n = 0; n < DSTATE; ++n) h[n] = sh_h[chunk][ch][n];
  const float dp = dpar[d];
  for (int s = 0; s < 32; ++s) {
    const int row = r0 + s;
    const float dl = dlt[(long)row * DINNER + d];
    const float xv = xs[(long)row * DINNER + d];
    const float dx = dl * xv;
    const float4* bp = (const float4*)(bc + (long)row * (2 * DSTATE));
    float Bv[DSTATE], Cv[DSTATE];
    *(float4*)&Bv[0]  = bp[0]; *(float4*)&Bv[4]  = bp[1];
    *(float4*)&Bv[8]  = bp[2]; *(float4*)&Bv[12] = bp[3];
    *(float4*)&Cv[0]  = bp[4]; *(float4*)&Cv[4]  = bp[5];
    *(float4*)&Cv[8]  = bp[6]; *(float4*)&Cv[12] = bp[7];
    float y = 0.f;
#pragma unroll
    for (int n = 0; n < DSTATE; ++n) {
      const float hn = __expf(dl * An[n]) * h[n] + dx * Bv[n];
      h[n] = hn;
      y += Cv[n] * hn;
    }
    y += dp * xv;
    const float zz = xz[(long)row * (2 * DINNER) + DINNER + d];
    const float o = y * (zz / (1.f + __expf(-zz)));
    ybf[(long)row * DINNER + d] = f2bf(o);
  }
}

// ---------------------------------------------------------------- RMSNorm -> bf16
__global__ __launch_bounds__(256) void rmsnorm_kern(const float* __restrict__ x,
                                                    const float* __restrict__ nw,
                                                    u16* __restrict__ xnbf) {
  const int row = blockIdx.x, tid = threadIdx.x;
  const float* xr = x + (long)row * DMODEL;
  float p = 0.f;
#pragma unroll
  for (int k = 0; k < 3; ++k) { float v = xr[tid + k * 256]; p += v * v; }
#pragma unroll
  for (int off = 32; off; off >>= 1) p += __shfl_xor(p, off, 64);
  __shared__ float red[4];
  __shared__ float s_rms;
  const int wv = tid >> 6, lane = tid & 63;
  if (lane == 0) red[wv] = p;
  __syncthreads();
  if (tid == 0) {
    float tsum = red[0] + red[1] + red[2] + red[3];
    s_rms = rsqrtf(tsum / (float)DMODEL + 1e-5f);
  }
  __syncthreads();
  const float r = s_rms;
#pragma unroll
  for (int k = 0; k < 3; ++k) {
    const int dd = tid + k * 256;
    xnbf[(long)row * DMODEL + dd] = f2bf(xr[dd] * r * nw[dd]);
  }
}

// ---------------------------------------------------------------- host
extern "C" void kernel_launch(void* const* d_in, const int* in_sizes, int n_in,
                              void* d_out, int out_size, void* d_ws, size_t ws_size,
                              hipStream_t stream)
{
  (void)in_sizes; (void)n_in; (void)out_size; (void)ws_size;
  const int*   idx   = (const int*)  d_in[0];
  const float* emb   = (const float*)d_in[1];
  const float* W_in  = (const float*)d_in[2];
  const float* convw = (const float*)d_in[3];
  const float* W_xp  = (const float*)d_in[4];
  const float* W_dt  = (const float*)d_in[5];
  const float* b_dt  = (const float*)d_in[6];
  const float* a_log = (const float*)d_in[7];
  const float* d_par = (const float*)d_in[8];
  const float* W_out = (const float*)d_in[9];
  const float* normw = (const float*)d_in[10];
  float* out = (float*)d_out;

  char* ws = (char*)d_ws;
  size_t off = 0;
  auto alloc = [&](size_t bytes) -> void* {
    void* p = ws + off;
    off += (bytes + 255) & ~(size_t)255;
    return p;
  };
  u16*   embbf  = (u16*)  alloc((size_t)VPAD * DMODEL * 2);
  u16*   winbf  = (u16*)  alloc((size_t)NLAYER * 2 * DINNER * DMODEL * 2);
  u16*   woutbf = (u16*)  alloc((size_t)NLAYER * DMODEL * DINNER * 2);
  float* xf     = (float*)alloc((size_t)MROWS * DMODEL * 4);
  u16*   xbf    = (u16*)  alloc((size_t)MROWS * DMODEL * 2);
  float* xz     = (float*)alloc((size_t)MROWS * 2 * DINNER * 4);
  float* xs     = (float*)alloc((size_t)MROWS * DINNER * 4);
  float* dlt    = (float*)alloc((size_t)MROWS * DINNER * 4);
  float* bc     = (float*)alloc((size_t)MROWS * 2 * DSTATE * 4);
  u16*   ybf    = (u16*)  alloc((size_t)MROWS * DINNER * 2);
  u16*   xnbf   = (u16*)  alloc((size_t)MROWS * DMODEL * 2);
  float* part   = (float*)alloc((size_t)4 * MROWS * DMODEL * 4);

  prep_kern<<<2048, 256, 0, stream>>>(emb, W_in, W_out, idx, embbf, winbf, woutbf, xf, xbf);

  for (int l = 0; l < NLAYER; ++l) {
    // xz = x @ W_in^T   (M=1024, N=3072, K=768)
    gemm3_kern<false, true><<<8 * (2 * DINNER / 128), 256, 0, stream>>>(
        xbf, winbf + (size_t)l * 2 * DINNER * DMODEL, xz,
        MROWS, 2 * DINNER, DMODEL, DMODEL, DMODEL);
    convxproj_kern<<<MROWS, 256, 0, stream>>>(
        xz, convw + (size_t)l * DINNER * DCONV,
        W_xp + (size_t)l * (2 * DSTATE + 1) * DINNER,
        W_dt + (size_t)l * DINNER, b_dt + (size_t)l * DINNER, xs, dlt, bc);
    scan_kern<<<BATCH * DINNER / 8, 128, 0, stream>>>(
        dlt, bc, xs, xz, a_log + (size_t)l * DINNER * DSTATE, d_par + (size_t)l * DINNER, ybf);
    // out-proj split-K x4: partials (M=1024, N=768, Kseg=384)
    gemm3_kern<false, true><<<dim3(8 * (DMODEL / 128), 1, 4), 256, 0, stream>>>(
        ybf, woutbf + (size_t)l * DMODEL * DINNER, part,
        MROWS, DMODEL, DINNER / 4, DINNER, DINNER);
    redout_kern<<<MROWS * DMODEL / 4 / 256, 256, 0, stream>>>(part, xf, xbf);
  }
  rmsnorm_kern<<<MROWS, 256, 0, stream>>>(xf, normw, xnbf);
  // logits = xn @ emb^T  (M=1024, N=50257, K=768)
  gemm3_kern<true, true><<<8 * (VPAD / 128), 256, 0, stream>>>(
      xnbf, embbf, out, MROWS, VV, DMODEL, DMODEL, DMODEL);
}

// Round 4
// 896.312 us; speedup vs baseline: 1.1932x; 1.0251x over previous
//
#include <hip/hip_runtime.h>
#include <cstdint>

#define VV     50257
#define VPAD   50432   // 197 * 256
#define DMODEL 768
#define NLAYER 4
#define DINNER 1536
#define DSTATE 16
#define DCONV  4
#define BATCH  2
#define SEQ    512
#define MROWS  (BATCH*SEQ)   // 1024

typedef unsigned short u16;
typedef __attribute__((ext_vector_type(8))) short bf16x8;
typedef __attribute__((ext_vector_type(4))) float f32x4;

__device__ __forceinline__ u16 f2bf(float f) {
  unsigned u = __float_as_uint(f);
  u += 0x7fffu + ((u >> 16) & 1u);
  return (u16)(u >> 16);
}

__device__ __forceinline__ void async16(const void* g, void* l) {
  auto gp = reinterpret_cast<const __attribute__((address_space(1))) unsigned int*>(
      reinterpret_cast<uintptr_t>(g));
  auto lp = reinterpret_cast<__attribute__((address_space(3))) unsigned int*>(
      reinterpret_cast<uintptr_t>(l));
  __builtin_amdgcn_global_load_lds(gp, lp, 16, 0, 0);
}

// ---------------------------------------------------------------- fused prep
__global__ void prep_kern(const float* __restrict__ emb, const float* __restrict__ W_in,
                          const float* __restrict__ W_out, const int* __restrict__ idx,
                          u16* __restrict__ embbf, u16* __restrict__ winbf,
                          u16* __restrict__ woutbf, float* __restrict__ xf,
                          u16* __restrict__ xbf) {
  const int E4  = VPAD * DMODEL / 4;
  const int W14 = NLAYER * 2 * DINNER * DMODEL / 4;
  const int W24 = NLAYER * DMODEL * DINNER / 4;
  const int X4  = MROWS * DMODEL / 4;
  const int TOT = E4 + W14 + W24 + X4;
  int i = blockIdx.x * blockDim.x + threadIdx.x;
  const int stride = gridDim.x * blockDim.x;
  for (; i < TOT; i += stride) {
    if (i < E4) {
      ushort4 o;
      if (i < VV * DMODEL / 4) {
        float4 v = *(const float4*)(emb + (long)i * 4);
        o.x = f2bf(v.x); o.y = f2bf(v.y); o.z = f2bf(v.z); o.w = f2bf(v.w);
      } else { o.x = 0; o.y = 0; o.z = 0; o.w = 0; }
      *(ushort4*)(embbf + (long)i * 4) = o;
    } else if (i < E4 + W14) {
      const int j = i - E4;
      float4 v = *(const float4*)(W_in + (long)j * 4);
      ushort4 o; o.x = f2bf(v.x); o.y = f2bf(v.y); o.z = f2bf(v.z); o.w = f2bf(v.w);
      *(ushort4*)(winbf + (long)j * 4) = o;
    } else if (i < E4 + W14 + W24) {
      const int j = i - E4 - W14;
      float4 v = *(const float4*)(W_out + (long)j * 4);
      ushort4 o; o.x = f2bf(v.x); o.y = f2bf(v.y); o.z = f2bf(v.z); o.w = f2bf(v.w);
      *(ushort4*)(woutbf + (long)j * 4) = o;
    } else {
      const int j = i - E4 - W14 - W24;
      const int r = j / (DMODEL / 4);
      const int c = (j % (DMODEL / 4)) * 4;
      const int id = idx[r];
      float4 v = *(const float4*)(emb + (long)id * DMODEL + c);
      *(float4*)(xf + (long)r * DMODEL + c) = v;
      ushort4 o; o.x = f2bf(v.x); o.y = f2bf(v.y); o.z = f2bf(v.z); o.w = f2bf(v.w);
      *(ushort4*)(xbf + (long)r * DMODEL + c) = o;
    }
  }
}

// ---------------------------------------------------------------- 128^2 ring-3 GEMM (per-layer sizes)
template<bool GUARDN, bool XSWZ>
__global__ __launch_bounds__(256) void gemm3_kern(
    const u16* __restrict__ A, const u16* __restrict__ B,
    float* __restrict__ C, int M, int N, int K, int lda, int ldb)
{
  __shared__ u16 As[3][128 * 32];
  __shared__ u16 Bs[3][128 * 32];
  int bx, by;
  if (XSWZ) {
    const int nt = gridDim.x >> 3;
    const int t = (blockIdx.x & 7) * nt + (blockIdx.x >> 3);
    bx = t & 7; by = t >> 3;
  } else { bx = blockIdx.x; by = blockIdx.y; }
  const int koff = blockIdx.z * K;
  const long coff = (long)blockIdx.z * M * N;

  const int tid  = threadIdx.x;
  const int wave = tid >> 6;
  const int lane = tid & 63;
  const int wr = wave >> 1, wc = wave & 1;
  const int m0 = bx * 128;
  const int n0 = by * 128;

  const int srow = wave * 32 + (lane >> 2);
  const int sblk = ((lane & 3) ^ ((lane >> 3) & 3)) * 8;

  f32x4 acc[4][4];
#pragma unroll
  for (int i = 0; i < 4; ++i)
#pragma unroll
    for (int j = 0; j < 4; ++j) acc[i][j] = (f32x4){0.f, 0.f, 0.f, 0.f};

  const int arow = wr * 64 + (lane & 15);
  const int brow = wc * 64 + (lane & 15);
  const int sa   = (((lane >> 4) ^ ((lane >> 1) & 3)) << 3);

  const int KT = K / 32;
  auto stage = [&](int kt) {
    const int slot = kt % 3;
    const long kcol = (long)koff + kt * 32;
#pragma unroll
    for (int j = 0; j < 2; ++j) {
      async16(A + (long)(m0 + srow + j * 16) * lda + kcol + sblk,
              (char*)(As[slot]) + (wave * 32 + j * 16) * 64);
      async16(B + (long)(n0 + srow + j * 16) * ldb + kcol + sblk,
              (char*)(Bs[slot]) + (wave * 32 + j * 16) * 64);
    }
  };

  stage(0);
  stage(1);
  for (int t = 0; t < KT; ++t) {
    if (t + 2 < KT) {
      stage(t + 2);
      asm volatile("s_waitcnt vmcnt(8)" ::: "memory");
    } else if (t + 2 == KT) {
      asm volatile("s_waitcnt vmcnt(4)" ::: "memory");
    } else {
      asm volatile("s_waitcnt vmcnt(0)" ::: "memory");
    }
    __builtin_amdgcn_s_barrier();
    asm volatile("" ::: "memory");

    const int slot = t % 3;
    const u16* as = As[slot];
    const u16* bs = Bs[slot];
    bf16x8 af[4], bv[4];
#pragma unroll
    for (int i = 0; i < 4; ++i) af[i] = *(const bf16x8*)(as + (arow + 16 * i) * 32 + sa);
#pragma unroll
    for (int j = 0; j < 4; ++j) bv[j] = *(const bf16x8*)(bs + (brow + 16 * j) * 32 + sa);

    __builtin_amdgcn_s_setprio(1);
#pragma unroll
    for (int i = 0; i < 4; ++i)
#pragma unroll
      for (int j = 0; j < 4; ++j)
        acc[i][j] = __builtin_amdgcn_mfma_f32_16x16x32_bf16(af[i], bv[j], acc[i][j], 0, 0, 0);
    __builtin_amdgcn_s_setprio(0);

    asm volatile("" ::: "memory");
    __builtin_amdgcn_s_barrier();
    asm volatile("" ::: "memory");
  }

  const int rbase = m0 + wr * 64 + ((lane >> 4) << 2);
  const int cbase = n0 + wc * 64 + (lane & 15);
#pragma unroll
  for (int j = 0; j < 4; ++j) {
    const int col = cbase + j * 16;
    if (GUARDN && col >= N) continue;
#pragma unroll
    for (int i = 0; i < 4; ++i) {
#pragma unroll
      for (int r = 0; r < 4; ++r) {
        const int row = rbase + i * 16 + r;
        C[coff + (long)row * N + col] = acc[i][j][r];
      }
    }
  }
}

// ---------------------------------------------------------------- 256^2 8-phase GEMM (logits)
// M fixed = 1024 (4 M-tiles). 8 waves (2M x 4N), band-interleaved ownership:
// wave(wm,wn) C-rows: {qm*128 + wm*64 + mf*16}, C-cols: {qn*128 + wn*32 + nf*16}.
// LDS: 2 bufs x (A 256x64 + B 256x64) bf16 = 128 KB. One half-tile stage per phase.
// Counted vmcnt: (6)@ph1, (8)@ph4, (6)@ph5, (8)@ph8; final iter peeled (4)/(0).
__global__ __launch_bounds__(512, 2) void gemm8_kern(
    const u16* __restrict__ A, const u16* __restrict__ B,
    float* __restrict__ C, int N, int K, int lda, int ldb)
{
  __shared__ u16 lds[2][2][256 * 64];
  const int tid = threadIdx.x;
  const int wave = tid >> 6;
  const int lane = tid & 63;
  const int wm = wave >> 2, wn = wave & 3;

  // bijective XCD swizzle (m204): works for nwg % 8 != 0
  const int nwg = gridDim.x;
  const int q = nwg >> 3, r = nwg & 7;
  const int xcd = blockIdx.x & 7;
  const int t = (xcd < r ? xcd * (q + 1) : r * (q + 1) + (xcd - r) * q) + (blockIdx.x >> 3);
  const int m0 = (t & 3) * 256;
  const int n0 = (t >> 2) * 256;

  const int NT = K / 64;        // K-tiles
  const int NI = NT / 2;        // iterations

  // staging geometry: instr j covers rows half*128 + j*64 + wave*8 + (lane>>3),
  // 16B block (lane&7), pre-swizzled source block = (lane&7)^(lane>>3).
  const int sblk = (((lane & 7) ^ (lane >> 3)) << 3);
  auto stage = [&](int buf, int ab, int half, int kt) {
    const u16* Mat = ab ? B : A;
    const int ld = ab ? ldb : lda;
    const int tb = ab ? n0 : m0;
#pragma unroll
    for (int j = 0; j < 2; ++j) {
      const int rloc = half * 128 + j * 64 + wave * 8;   // wave-uniform
      async16(Mat + (long)(tb + rloc + (lane >> 3)) * ld + kt * 64 + sblk,
              (char*)&lds[buf][ab][0] + (rloc << 7));
    }
  };

  bf16x8 af[4][2], bl[2][2], bh[2][2];
  const int aq = lane >> 4;      // 16B-block quad within 32-k half
  auto readA = [&](int buf, int half) {
#pragma unroll
    for (int mf = 0; mf < 4; ++mf) {
      const int rr = half * 128 + wm * 64 + mf * 16 + (lane & 15);
#pragma unroll
      for (int ks = 0; ks < 2; ++ks) {
        const int q2 = ks * 4 + aq;
        af[mf][ks] = *(const bf16x8*)(&lds[buf][0][0] + rr * 64 + ((q2 ^ (rr & 7)) << 3));
      }
    }
  };
  auto readB = [&](int buf, int half, bf16x8 (&bf)[2][2]) {
#pragma unroll
    for (int nf = 0; nf < 2; ++nf) {
      const int rr = half * 128 + wn * 32 + nf * 16 + (lane & 15);
#pragma unroll
      for (int ks = 0; ks < 2; ++ks) {
        const int q2 = ks * 4 + aq;
        bf[nf][ks] = *(const bf16x8*)(&lds[buf][1][0] + rr * 64 + ((q2 ^ (rr & 7)) << 3));
      }
    }
  };

  f32x4 acc[8][4];
#pragma unroll
  for (int i = 0; i < 8; ++i)
#pragma unroll
    for (int j = 0; j < 4; ++j) acc[i][j] = (f32x4){0.f, 0.f, 0.f, 0.f};

#define MFMA16(QM, QN, BF)                                                        \
  __builtin_amdgcn_s_setprio(1);                                                  \
  _Pragma("unroll")                                                               \
  for (int mf = 0; mf < 4; ++mf)                                                  \
    _Pragma("unroll")                                                             \
    for (int nf = 0; nf < 2; ++nf)                                                \
      _Pragma("unroll")                                                           \
      for (int ks = 0; ks < 2; ++ks)                                              \
        acc[(QM)*4+mf][(QN)*2+nf] = __builtin_amdgcn_mfma_f32_16x16x32_bf16(      \
            af[mf][ks], BF[nf][ks], acc[(QM)*4+mf][(QN)*2+nf], 0, 0, 0);          \
  __builtin_amdgcn_s_setprio(0);

#define BAR()  asm volatile("" ::: "memory"); __builtin_amdgcn_s_barrier(); asm volatile("" ::: "memory")
#define LGKM0() asm volatile("s_waitcnt lgkmcnt(0)" ::: "memory")

  // prologue: kt0.A0, kt0.B0, kt0.B1, kt0.A1, kt1.A0, kt1.B0  (12 loads)
  stage(0, 0, 0, 0); stage(0, 1, 0, 0); stage(0, 1, 1, 0);
  stage(0, 0, 1, 0); stage(1, 0, 0, 1); stage(1, 1, 0, 1);
  asm volatile("s_waitcnt vmcnt(8)" ::: "memory");   // kt0.A0, kt0.B0 landed
  BAR();

  for (int it = 0; it < NI; ++it) {
    const int kt = it * 2;
    const bool last = (it == NI - 1);
    // ---- ph1: Q(0,0) of kt (buf0)
    readA(0, 0); readB(0, 0, bl);
    stage(1, 0, 1, kt + 1);                           // b1.A1
    asm volatile("s_waitcnt vmcnt(6)" ::: "memory");
    BAR(); LGKM0();
    MFMA16(0, 0, bl);
    BAR();
    // ---- ph2: Q(0,1)
    readB(0, 1, bh);
    stage(1, 1, 1, kt + 1);                           // b1.B1
    BAR(); LGKM0();
    MFMA16(0, 1, bh);
    BAR();
    // ---- ph3: Q(1,0)
    readA(0, 1);
    if (!last) stage(0, 0, 0, kt + 2);                // b0.A0
    BAR(); LGKM0();
    MFMA16(1, 0, bl);
    BAR();
    // ---- ph4: Q(1,1)
    if (!last) { stage(0, 1, 0, kt + 2);              // b0.B0
      asm volatile("s_waitcnt vmcnt(8)" ::: "memory");
    } else {
      asm volatile("s_waitcnt vmcnt(4)" ::: "memory");
    }
    BAR();
    MFMA16(1, 1, bh);
    BAR();
    // ---- ph5: Q(0,0) of kt+1 (buf1)
    readA(1, 0); readB(1, 0, bl);
    if (!last) { stage(0, 0, 1, kt + 2);              // b0.A1
      asm volatile("s_waitcnt vmcnt(6)" ::: "memory");
    } else {
      asm volatile("s_waitcnt vmcnt(0)" ::: "memory");
    }
    BAR(); LGKM0();
    MFMA16(0, 0, bl);
    BAR();
    // ---- ph6: Q(0,1)
    readB(1, 1, bh);
    if (!last) stage(0, 1, 1, kt + 2);                // b0.B1
    BAR(); LGKM0();
    MFMA16(0, 1, bh);
    BAR();
    // ---- ph7: Q(1,0)
    readA(1, 1);
    if (!last) stage(1, 0, 0, kt + 3);                // b1.A0
    BAR(); LGKM0();
    MFMA16(1, 0, bl);
    BAR();
    // ---- ph8: Q(1,1)
    if (!last) { stage(1, 1, 0, kt + 3);              // b1.B0
      asm volatile("s_waitcnt vmcnt(8)" ::: "memory");
    }
    BAR();
    MFMA16(1, 1, bh);
    if (!last) { BAR(); }
  }

  // epilogue: C-write. frag rows = qm*128 + wm*64 + mf*16 + (lane>>4)*4 + rr
#pragma unroll
  for (int qm = 0; qm < 2; ++qm)
#pragma unroll
    for (int mf = 0; mf < 4; ++mf)
#pragma unroll
      for (int qn = 0; qn < 2; ++qn)
#pragma unroll
        for (int nf = 0; nf < 2; ++nf) {
          const int col = n0 + qn * 128 + wn * 32 + nf * 16 + (lane & 15);
          if (col >= N) continue;
          const int row0 = m0 + qm * 128 + wm * 64 + mf * 16 + ((lane >> 4) << 2);
          const f32x4 v = acc[qm * 4 + mf][qn * 2 + nf];
#pragma unroll
          for (int rr2 = 0; rr2 < 4; ++rr2)
            C[(long)(row0 + rr2) * N + col] = v[rr2];
        }
#undef MFMA16
#undef BAR
#undef LGKM0
}

// ---------------------------------------------------------------- split-K reduce + residual + bf16
__global__ __launch_bounds__(256) void redout_kern(const float* __restrict__ part,
                                                   float* __restrict__ xf,
                                                   u16* __restrict__ xbf) {
  const int i = blockIdx.x * blockDim.x + threadIdx.x;
  if (i >= MROWS * DMODEL / 4) return;
  const int stride4 = MROWS * DMODEL / 4;
  float4 s = ((const float4*)part)[i];
  float4 p1 = ((const float4*)part)[i + stride4];
  float4 p2 = ((const float4*)part)[i + 2 * stride4];
  float4 p3 = ((const float4*)part)[i + 3 * stride4];
  float4 x = ((const float4*)xf)[i];
  s.x += p1.x + p2.x + p3.x + x.x;
  s.y += p1.y + p2.y + p3.y + x.y;
  s.z += p1.z + p2.z + p3.z + x.z;
  s.w += p1.w + p2.w + p3.w + x.w;
  ((float4*)xf)[i] = s;
  ushort4 o; o.x = f2bf(s.x); o.y = f2bf(s.y); o.z = f2bf(s.z); o.w = f2bf(s.w);
  ((ushort4*)xbf)[i] = o;
}

// ---------------------------------------------------------------- fused conv+SiLU+xproj+delta
__global__ __launch_bounds__(256) void convxproj_kern(
    const float* __restrict__ xz, const float* __restrict__ cw,
    const float* __restrict__ Wx, const float* __restrict__ wdt,
    const float* __restrict__ bdt,
    float* __restrict__ xs, float* __restrict__ dlt, float* __restrict__ bc)
{
  __shared__ float sx[DINNER];
  __shared__ float sxp[40];
  const int row = blockIdx.x;
  const int t = row & (SEQ - 1);
  const int tid = threadIdx.x;

  for (int c = tid; c < DINNER; c += 256) {
    const float* w = cw + c * DCONV;
    float a = 0.f;
#pragma unroll
    for (int k = 0; k < DCONV; ++k) {
      const int tt = t - (DCONV - 1) + k;
      if (tt >= 0) a += w[k] * xz[(long)(row - (DCONV - 1) + k) * (2 * DINNER) + c];
    }
    const float s = a / (1.f + __expf(-a));
    sx[c] = s;
    xs[(long)row * DINNER + c] = s;
  }
  __syncthreads();

  const int wv = tid >> 6, lane = tid & 63;
  for (int e = wv; e < 2 * DSTATE + 1; e += 4) {
    const float* We = Wx + (long)e * DINNER;
    float p = 0.f;
    for (int d = lane; d < DINNER; d += 64) p += sx[d] * We[d];
#pragma unroll
    for (int off = 32; off; off >>= 1) p += __shfl_xor(p, off, 64);
    if (lane == 0) sxp[e] = p;
  }
  __syncthreads();
  const float dtr = sxp[0];
  for (int d = tid; d < DINNER; d += 256) {
    float v = dtr * wdt[d] + bdt[d];
    float sp = (v > 15.f) ? v : log1pf(__expf(v));
    dlt[(long)row * DINNER + d] = sp;
  }
  if (tid < 2 * DSTATE) bc[(long)row * (2 * DSTATE) + tid] = sxp[1 + tid];
}

// ---------------------------------------------------------------- chunked selective scan + gate
__global__ __launch_bounds__(128) void scan_kern(
    const float* __restrict__ dlt, const float* __restrict__ bc,
    const float* __restrict__ xs, const float* __restrict__ xz,
    const float* __restrict__ alog, const float* __restrict__ dpar,
    u16* __restrict__ ybf)
{
  __shared__ float sh_h[16][8][DSTATE];
  __shared__ float sh_s[16][8];
  const int tid = threadIdx.x;
  const int ch = tid & 7, chunk = tid >> 3;
  const int ch_abs = blockIdx.x * 8 + ch;
  const int b = ch_abs / DINNER, d = ch_abs % DINNER;
  float An[DSTATE];
#pragma unroll
  for (int n = 0; n < DSTATE; ++n) An[n] = -__expf(alog[(long)d * DSTATE + n]);
  const int r0 = b * SEQ + chunk * 32;

  float h[DSTATE];
#pragma unroll
  for (int n = 0; n < DSTATE; ++n) h[n] = 0.f;
  float ssum = 0.f;
  for (int s = 0; s < 32; ++s) {
    const int row = r0 + s;
    const float dl = dlt[(long)row * DINNER + d];
    const float xv = xs[(long)row * DINNER + d];
    const float dx = dl * xv;
    const float4* bp = (const float4*)(bc + (long)row * (2 * DSTATE));
    float Bv[DSTATE];
    *(float4*)&Bv[0]  = bp[0]; *(float4*)&Bv[4]  = bp[1];
    *(float4*)&Bv[8]  = bp[2]; *(float4*)&Bv[12] = bp[3];
    ssum += dl;
#pragma unroll
    for (int n = 0; n < DSTATE; ++n) h[n] = __expf(dl * An[n]) * h[n] + dx * Bv[n];
  }
#pragma unroll
  for (int n = 0; n < DSTATE; ++n) sh_h[chunk][ch][n] = h[n];
  sh_s[chunk][ch] = ssum;
  __syncthreads();

  {
    const int n2 = tid & 15, ch2 = tid >> 4;
    const int d2 = (blockIdx.x * 8 + ch2) % DINNER;
    const float A2 = -__expf(alog[(long)d2 * DSTATE + n2]);
    float carry = 0.f;
    for (int c = 0; c < 16; ++c) {
      const float hl = sh_h[c][ch2][n2];
      sh_h[c][ch2][n2] = carry;
      carry = __expf(A2 * sh_s[c][ch2]) * carry + hl;
    }
  }
  __syncthreads();

#pragma unroll
  for (int n = 0; n < DSTATE; ++n) h[n] = sh_h[chunk][ch][n];
  const float dp = dpar[d];
  for (int s = 0; s < 32; ++s) {
    const int row = r0 + s;
    const float dl = dlt[(long)row * DINNER + d];
    const float xv = xs[(long)row * DINNER + d];
    const float dx = dl * xv;
    const float4* bp = (const float4*)(bc + (long)row * (2 * DSTATE));
    float Bv[DSTATE], Cv[DSTATE];
    *(float4*)&Bv[0]  = bp[0]; *(float4*)&Bv[4]  = bp[1];
    *(float4*)&Bv[8]  = bp[2]; *(float4*)&Bv[12] = bp[3];
    *(float4*)&Cv[0]  = bp[4]; *(float4*)&Cv[4]  = bp[5];
    *(float4*)&Cv[8]  = bp[6]; *(float4*)&Cv[12] = bp[7];
    float y = 0.f;
#pragma unroll
    for (int n = 0; n < DSTATE; ++n) {
      const float hn = __expf(dl * An[n]) * h[n] + dx * Bv[n];
      h[n] = hn;
      y += Cv[n] * hn;
    }
    y += dp * xv;
    const float zz = xz[(long)row * (2 * DINNER) + DINNER + d];
    const float o = y * (zz / (1.f + __expf(-zz)));
    ybf[(long)row * DINNER + d] = f2bf(o);
  }
}

// ---------------------------------------------------------------- RMSNorm -> bf16
__global__ __launch_bounds__(256) void rmsnorm_kern(const float* __restrict__ x,
                                                    const float* __restrict__ nw,
                                                    u16* __restrict__ xnbf) {
  const int row = blockIdx.x, tid = threadIdx.x;
  const float* xr = x + (long)row * DMODEL;
  float p = 0.f;
#pragma unroll
  for (int k = 0; k < 3; ++k) { float v = xr[tid + k * 256]; p += v * v; }
#pragma unroll
  for (int off = 32; off; off >>= 1) p += __shfl_xor(p, off, 64);
  __shared__ float red[4];
  __shared__ float s_rms;
  const int wv = tid >> 6, lane = tid & 63;
  if (lane == 0) red[wv] = p;
  __syncthreads();
  if (tid == 0) {
    float tsum = red[0] + red[1] + red[2] + red[3];
    s_rms = rsqrtf(tsum / (float)DMODEL + 1e-5f);
  }
  __syncthreads();
  const float r = s_rms;
#pragma unroll
  for (int k = 0; k < 3; ++k) {
    const int dd = tid + k * 256;
    xnbf[(long)row * DMODEL + dd] = f2bf(xr[dd] * r * nw[dd]);
  }
}

// ---------------------------------------------------------------- host
extern "C" void kernel_launch(void* const* d_in, const int* in_sizes, int n_in,
                              void* d_out, int out_size, void* d_ws, size_t ws_size,
                              hipStream_t stream)
{
  (void)in_sizes; (void)n_in; (void)out_size; (void)ws_size;
  const int*   idx   = (const int*)  d_in[0];
  const float* emb   = (const float*)d_in[1];
  const float* W_in  = (const float*)d_in[2];
  const float* convw = (const float*)d_in[3];
  const float* W_xp  = (const float*)d_in[4];
  const float* W_dt  = (const float*)d_in[5];
  const float* b_dt  = (const float*)d_in[6];
  const float* a_log = (const float*)d_in[7];
  const float* d_par = (const float*)d_in[8];
  const float* W_out = (const float*)d_in[9];
  const float* normw = (const float*)d_in[10];
  float* out = (float*)d_out;

  char* ws = (char*)d_ws;
  size_t off = 0;
  auto alloc = [&](size_t bytes) -> void* {
    void* p = ws + off;
    off += (bytes + 255) & ~(size_t)255;
    return p;
  };
  u16*   embbf  = (u16*)  alloc((size_t)VPAD * DMODEL * 2);
  u16*   winbf  = (u16*)  alloc((size_t)NLAYER * 2 * DINNER * DMODEL * 2);
  u16*   woutbf = (u16*)  alloc((size_t)NLAYER * DMODEL * DINNER * 2);
  float* xf     = (float*)alloc((size_t)MROWS * DMODEL * 4);
  u16*   xbf    = (u16*)  alloc((size_t)MROWS * DMODEL * 2);
  float* xz     = (float*)alloc((size_t)MROWS * 2 * DINNER * 4);
  float* xs     = (float*)alloc((size_t)MROWS * DINNER * 4);
  float* dlt    = (float*)alloc((size_t)MROWS * DINNER * 4);
  float* bc     = (float*)alloc((size_t)MROWS * 2 * DSTATE * 4);
  u16*   ybf    = (u16*)  alloc((size_t)MROWS * DINNER * 2);
  u16*   xnbf   = (u16*)  alloc((size_t)MROWS * DMODEL * 2);
  float* part   = (float*)alloc((size_t)4 * MROWS * DMODEL * 4);

  prep_kern<<<2048, 256, 0, stream>>>(emb, W_in, W_out, idx, embbf, winbf, woutbf, xf, xbf);

  for (int l = 0; l < NLAYER; ++l) {
    gemm3_kern<false, true><<<8 * (2 * DINNER / 128), 256, 0, stream>>>(
        xbf, winbf + (size_t)l * 2 * DINNER * DMODEL, xz,
        MROWS, 2 * DINNER, DMODEL, DMODEL, DMODEL);
    convxproj_kern<<<MROWS, 256, 0, stream>>>(
        xz, convw + (size_t)l * DINNER * DCONV,
        W_xp + (size_t)l * (2 * DSTATE + 1) * DINNER,
        W_dt + (size_t)l * DINNER, b_dt + (size_t)l * DINNER, xs, dlt, bc);
    scan_kern<<<BATCH * DINNER / 8, 128, 0, stream>>>(
        dlt, bc, xs, xz, a_log + (size_t)l * DINNER * DSTATE, d_par + (size_t)l * DINNER, ybf);
    gemm3_kern<false, true><<<dim3(8 * (DMODEL / 128), 1, 4), 256, 0, stream>>>(
        ybf, woutbf + (size_t)l * DMODEL * DINNER, part,
        MROWS, DMODEL, DINNER / 4, DINNER, DINNER);
    redout_kern<<<MROWS * DMODEL / 4 / 256, 256, 0, stream>>>(part, xf, xbf);
  }
  rmsnorm_kern<<<MROWS, 256, 0, stream>>>(xf, normw, xnbf);
  // logits = xn @ emb^T  (M=1024, N=50257, K=768), 256^2 8-phase
  gemm8_kern<<<4 * (VPAD / 256), 512, 0, stream>>>(
      xnbf, embbf, out, VV, DMODEL, DMODEL, DMODEL);
}

// Round 5
// 883.543 us; speedup vs baseline: 1.2105x; 1.0145x over previous
//
#include <hip/hip_runtime.h>
#include <cstdint>

#define VV     50257
#define VPAD   50432   // 197 * 256
#define DMODEL 768
#define NLAYER 4
#define DINNER 1536
#define DSTATE 16
#define DCONV  4
#define BATCH  2
#define SEQ    512
#define MROWS  (BATCH*SEQ)   // 1024

typedef unsigned short u16;
typedef __attribute__((ext_vector_type(8))) short bf16x8;
typedef __attribute__((ext_vector_type(4))) float f32x4;

__device__ __forceinline__ u16 f2bf(float f) {
  unsigned u = __float_as_uint(f);
  u += 0x7fffu + ((u >> 16) & 1u);
  return (u16)(u >> 16);
}

__device__ __forceinline__ void async16(const void* g, void* l) {
  auto gp = reinterpret_cast<const __attribute__((address_space(1))) unsigned int*>(
      reinterpret_cast<uintptr_t>(g));
  auto lp = reinterpret_cast<__attribute__((address_space(3))) unsigned int*>(
      reinterpret_cast<uintptr_t>(l));
  __builtin_amdgcn_global_load_lds(gp, lp, 16, 0, 0);
}

// ---------------------------------------------------------------- fused prep
__global__ void prep_kern(const float* __restrict__ emb, const float* __restrict__ W_in,
                          const float* __restrict__ W_out, const int* __restrict__ idx,
                          u16* __restrict__ embbf, u16* __restrict__ winbf,
                          u16* __restrict__ woutbf, float* __restrict__ xf,
                          u16* __restrict__ xbf) {
  const int E4  = VPAD * DMODEL / 4;
  const int W14 = NLAYER * 2 * DINNER * DMODEL / 4;
  const int W24 = NLAYER * DMODEL * DINNER / 4;
  const int X4  = MROWS * DMODEL / 4;
  const int TOT = E4 + W14 + W24 + X4;
  int i = blockIdx.x * blockDim.x + threadIdx.x;
  const int stride = gridDim.x * blockDim.x;
  for (; i < TOT; i += stride) {
    if (i < E4) {
      ushort4 o;
      if (i < VV * DMODEL / 4) {
        float4 v = *(const float4*)(emb + (long)i * 4);
        o.x = f2bf(v.x); o.y = f2bf(v.y); o.z = f2bf(v.z); o.w = f2bf(v.w);
      } else { o.x = 0; o.y = 0; o.z = 0; o.w = 0; }
      *(ushort4*)(embbf + (long)i * 4) = o;
    } else if (i < E4 + W14) {
      const int j = i - E4;
      float4 v = *(const float4*)(W_in + (long)j * 4);
      ushort4 o; o.x = f2bf(v.x); o.y = f2bf(v.y); o.z = f2bf(v.z); o.w = f2bf(v.w);
      *(ushort4*)(winbf + (long)j * 4) = o;
    } else if (i < E4 + W14 + W24) {
      const int j = i - E4 - W14;
      float4 v = *(const float4*)(W_out + (long)j * 4);
      ushort4 o; o.x = f2bf(v.x); o.y = f2bf(v.y); o.z = f2bf(v.z); o.w = f2bf(v.w);
      *(ushort4*)(woutbf + (long)j * 4) = o;
    } else {
      const int j = i - E4 - W14 - W24;
      const int r = j / (DMODEL / 4);
      const int c = (j % (DMODEL / 4)) * 4;
      const int id = idx[r];
      float4 v = *(const float4*)(emb + (long)id * DMODEL + c);
      *(float4*)(xf + (long)r * DMODEL + c) = v;
      ushort4 o; o.x = f2bf(v.x); o.y = f2bf(v.y); o.z = f2bf(v.z); o.w = f2bf(v.w);
      *(ushort4*)(xbf + (long)r * DMODEL + c) = o;
    }
  }
}

// ---------------------------------------------------------------- 128^2 ring-3 GEMM (per-layer sizes)
template<bool GUARDN, bool XSWZ>
__global__ __launch_bounds__(256) void gemm3_kern(
    const u16* __restrict__ A, const u16* __restrict__ B,
    float* __restrict__ C, int M, int N, int K, int lda, int ldb)
{
  __shared__ u16 As[3][128 * 32];
  __shared__ u16 Bs[3][128 * 32];
  int bx, by;
  if (XSWZ) {
    const int nt = gridDim.x >> 3;
    const int t = (blockIdx.x & 7) * nt + (blockIdx.x >> 3);
    bx = t & 7; by = t >> 3;
  } else { bx = blockIdx.x; by = blockIdx.y; }
  const int koff = blockIdx.z * K;
  const long coff = (long)blockIdx.z * M * N;

  const int tid  = threadIdx.x;
  const int wave = tid >> 6;
  const int lane = tid & 63;
  const int wr = wave >> 1, wc = wave & 1;
  const int m0 = bx * 128;
  const int n0 = by * 128;

  const int srow = wave * 32 + (lane >> 2);
  const int sblk = ((lane & 3) ^ ((lane >> 3) & 3)) * 8;

  f32x4 acc[4][4];
#pragma unroll
  for (int i = 0; i < 4; ++i)
#pragma unroll
    for (int j = 0; j < 4; ++j) acc[i][j] = (f32x4){0.f, 0.f, 0.f, 0.f};

  const int arow = wr * 64 + (lane & 15);
  const int brow = wc * 64 + (lane & 15);
  const int sa   = (((lane >> 4) ^ ((lane >> 1) & 3)) << 3);

  const int KT = K / 32;
  auto stage = [&](int kt) {
    const int slot = kt % 3;
    const long kcol = (long)koff + kt * 32;
#pragma unroll
    for (int j = 0; j < 2; ++j) {
      async16(A + (long)(m0 + srow + j * 16) * lda + kcol + sblk,
              (char*)(As[slot]) + (wave * 32 + j * 16) * 64);
      async16(B + (long)(n0 + srow + j * 16) * ldb + kcol + sblk,
              (char*)(Bs[slot]) + (wave * 32 + j * 16) * 64);
    }
  };

  stage(0);
  stage(1);
  for (int t = 0; t < KT; ++t) {
    if (t + 2 < KT) {
      stage(t + 2);
      asm volatile("s_waitcnt vmcnt(8)" ::: "memory");
    } else if (t + 2 == KT) {
      asm volatile("s_waitcnt vmcnt(4)" ::: "memory");
    } else {
      asm volatile("s_waitcnt vmcnt(0)" ::: "memory");
    }
    __builtin_amdgcn_s_barrier();
    asm volatile("" ::: "memory");

    const int slot = t % 3;
    const u16* as = As[slot];
    const u16* bs = Bs[slot];
    bf16x8 af[4], bv[4];
#pragma unroll
    for (int i = 0; i < 4; ++i) af[i] = *(const bf16x8*)(as + (arow + 16 * i) * 32 + sa);
#pragma unroll
    for (int j = 0; j < 4; ++j) bv[j] = *(const bf16x8*)(bs + (brow + 16 * j) * 32 + sa);

    __builtin_amdgcn_s_setprio(1);
#pragma unroll
    for (int i = 0; i < 4; ++i)
#pragma unroll
      for (int j = 0; j < 4; ++j)
        acc[i][j] = __builtin_amdgcn_mfma_f32_16x16x32_bf16(af[i], bv[j], acc[i][j], 0, 0, 0);
    __builtin_amdgcn_s_setprio(0);

    asm volatile("" ::: "memory");
    __builtin_amdgcn_s_barrier();
    asm volatile("" ::: "memory");
  }

  const int rbase = m0 + wr * 64 + ((lane >> 4) << 2);
  const int cbase = n0 + wc * 64 + (lane & 15);
#pragma unroll
  for (int j = 0; j < 4; ++j) {
    const int col = cbase + j * 16;
    if (GUARDN && col >= N) continue;
#pragma unroll
    for (int i = 0; i < 4; ++i) {
#pragma unroll
      for (int r = 0; r < 4; ++r) {
        const int row = rbase + i * 16 + r;
        C[coff + (long)row * N + col] = acc[i][j][r];
      }
    }
  }
}

// ---------------------------------------------------------------- 256^2 4-phase pipelined GEMM (logits)
// 8 waves (2M x 4N); wave C-tile = rows {qm*128+wm*64+mf*16}, cols {qn*128+wn*32+nf*16}.
// Per K-tile (BK=64): 4 phases Q00,Q01,Q10,Q11; ONE barrier per phase.
// Reads: af0(kt)+bh(kt)@Q00 (in-phase af0, prefetch bh), af1(kt)@Q10, bl(kt+1)@Q11 (prefetch).
// Stages (2 gloads each): A1(kt+1)@Q00(kt), A0(kt+2)@Q01, B0(kt+2)@Q10, B1(kt+2)@Q11.
// vmcnt tops: Q00(8), Q01(-), Q10(10), Q11(8); lgkm: 4,0,0,4. Derived per issue history.
__global__ __launch_bounds__(512, 2) void gemm8_kern(
    const u16* __restrict__ A, const u16* __restrict__ B,
    float* __restrict__ C, int N, int K, int lda, int ldb)
{
  __shared__ u16 lds[2][2][256 * 64];
  const int tid = threadIdx.x;
  const int wave = tid >> 6;
  const int lane = tid & 63;
  const int wm = wave >> 2, wn = wave & 3;

  // bijective XCD swizzle (m204)
  const int nwg = gridDim.x;
  const int q = nwg >> 3, r = nwg & 7;
  const int xcd = blockIdx.x & 7;
  const int t = (xcd < r ? xcd * (q + 1) : r * (q + 1) + (xcd - r) * q) + (blockIdx.x >> 3);
  const int m0 = (t & 3) * 256;
  const int n0 = (t >> 2) * 256;

  const int NT = K / 64;        // 12 K-tiles

  const int sblk = (((lane & 7) ^ (lane >> 3)) << 3);
  auto stage = [&](int buf, int ab, int half, int kt) {
    const u16* Mat = ab ? B : A;
    const int ld = ab ? ldb : lda;
    const int tb = ab ? n0 : m0;
#pragma unroll
    for (int j = 0; j < 2; ++j) {
      const int rloc = half * 128 + j * 64 + wave * 8;   // wave-uniform
      async16(Mat + (long)(tb + rloc + (lane >> 3)) * ld + kt * 64 + sblk,
              (char*)&lds[buf][ab][0] + (rloc << 7));
    }
  };

  bf16x8 af[4][2], bl[2][2], bh[2][2];
  const int aq = lane >> 4;
  auto readA = [&](int buf, int half) {
#pragma unroll
    for (int mf = 0; mf < 4; ++mf) {
      const int rr = half * 128 + wm * 64 + mf * 16 + (lane & 15);
#pragma unroll
      for (int ks = 0; ks < 2; ++ks) {
        const int q2 = ks * 4 + aq;
        af[mf][ks] = *(const bf16x8*)(&lds[buf][0][0] + rr * 64 + ((q2 ^ (rr & 7)) << 3));
      }
    }
  };
  auto readB = [&](int buf, int half, bf16x8 (&bf)[2][2]) {
#pragma unroll
    for (int nf = 0; nf < 2; ++nf) {
      const int rr = half * 128 + wn * 32 + nf * 16 + (lane & 15);
#pragma unroll
      for (int ks = 0; ks < 2; ++ks) {
        const int q2 = ks * 4 + aq;
        bf[nf][ks] = *(const bf16x8*)(&lds[buf][1][0] + rr * 64 + ((q2 ^ (rr & 7)) << 3));
      }
    }
  };

  f32x4 acc[8][4];
#pragma unroll
  for (int i = 0; i < 8; ++i)
#pragma unroll
    for (int j = 0; j < 4; ++j) acc[i][j] = (f32x4){0.f, 0.f, 0.f, 0.f};

#define MFMA16(QM, QN, BF)                                                        \
  __builtin_amdgcn_s_setprio(1);                                                  \
  _Pragma("unroll")                                                               \
  for (int mf = 0; mf < 4; ++mf)                                                  \
    _Pragma("unroll")                                                             \
    for (int nf = 0; nf < 2; ++nf)                                                \
      _Pragma("unroll")                                                           \
      for (int ks = 0; ks < 2; ++ks)                                              \
        acc[(QM)*4+mf][(QN)*2+nf] = __builtin_amdgcn_mfma_f32_16x16x32_bf16(      \
            af[mf][ks], BF[nf][ks], acc[(QM)*4+mf][(QN)*2+nf], 0, 0, 0);          \
  __builtin_amdgcn_s_setprio(0);

#define BAR()   asm volatile("" ::: "memory"); __builtin_amdgcn_s_barrier(); asm volatile("" ::: "memory")
#define WAITV(N) asm volatile("s_waitcnt vmcnt(" #N ")" ::: "memory"); __builtin_amdgcn_sched_barrier(0)
#define WAITL(N) asm volatile("s_waitcnt lgkmcnt(" #N ")" ::: "memory"); __builtin_amdgcn_sched_barrier(0)

  // prologue: stage kt0{A0,B0,B1,A1}, kt1{A0,B0,B1}; land kt0; read bl(0)
  stage(0, 0, 0, 0); stage(0, 1, 0, 0); stage(0, 1, 1, 0); stage(0, 0, 1, 0);
  stage(1, 0, 0, 1); stage(1, 1, 0, 1); stage(1, 1, 1, 1);
  WAITV(6);
  BAR();
  readB(0, 0, bl);                       // bl(0)

#define TILE(KTE, BUF)                                                            \
  {                                                                               \
    const int kt = (KTE);                                                         \
    /* ---- Q00 ---- */                                                           \
    if (kt >= NT - 2) { WAITV(0); } else { WAITV(8); }                            \
    BAR();                                                                        \
    readA(BUF, 0);                       /* af0(kt), 8 reads */                   \
    readB(BUF, 1, bh);                   /* bh(kt), 4 reads (prefetch) */         \
    if (kt + 1 < NT) stage(BUF ^ 1, 0, 1, kt + 1);   /* A1(kt+1) */               \
    WAITL(4);                            /* forces bl(kt)+af0; bh pending */      \
    MFMA16(0, 0, bl);                                                             \
    /* ---- Q01 ---- */                                                           \
    BAR();                                                                        \
    if (kt + 2 < NT) stage(BUF, 0, 0, kt + 2);       /* A0(kt+2) */               \
    WAITL(0);                            /* forces bh */                          \
    MFMA16(0, 1, bh);                                                             \
    /* ---- Q10 ---- */                                                           \
    if (kt >= NT - 2) { WAITV(0); } else { WAITV(10); }                           \
    BAR();                                                                        \
    readA(BUF, 1);                       /* af1(kt), 8 reads (WAR on af ok) */    \
    if (kt + 2 < NT) stage(BUF, 1, 0, kt + 2);       /* B0(kt+2) */               \
    WAITL(0);                            /* forces af1 */                         \
    MFMA16(1, 0, bl);                                                             \
    /* ---- Q11 ---- */                                                           \
    if (kt >= NT - 2) { WAITV(0); } else { WAITV(8); }                            \
    BAR();                                                                        \
    if (kt + 1 < NT) readB(BUF ^ 1, 0, bl);          /* bl(kt+1), prefetch */     \
    if (kt + 2 < NT) stage(BUF, 1, 1, kt + 2);       /* B1(kt+2) */               \
    WAITL(4);                            /* bl(kt+1) may stay pending */          \
    MFMA16(1, 1, bh);                                                             \
  }

  for (int kt2 = 0; kt2 < NT; kt2 += 2) {
    TILE(kt2, 0);
    TILE(kt2 + 1, 1);
  }

  // epilogue
#pragma unroll
  for (int qm = 0; qm < 2; ++qm)
#pragma unroll
    for (int mf = 0; mf < 4; ++mf)
#pragma unroll
      for (int qn = 0; qn < 2; ++qn)
#pragma unroll
        for (int nf = 0; nf < 2; ++nf) {
          const int col = n0 + qn * 128 + wn * 32 + nf * 16 + (lane & 15);
          if (col >= N) continue;
          const int row0 = m0 + qm * 128 + wm * 64 + mf * 16 + ((lane >> 4) << 2);
          const f32x4 v = acc[qm * 4 + mf][qn * 2 + nf];
#pragma unroll
          for (int rr2 = 0; rr2 < 4; ++rr2)
            C[(long)(row0 + rr2) * N + col] = v[rr2];
        }
#undef TILE
#undef MFMA16
#undef BAR
#undef WAITV
#undef WAITL
}

// ---------------------------------------------------------------- split-K reduce + residual + bf16
__global__ __launch_bounds__(256) void redout_kern(const float* __restrict__ part,
                                                   float* __restrict__ xf,
                                                   u16* __restrict__ xbf) {
  const int i = blockIdx.x * blockDim.x + threadIdx.x;
  if (i >= MROWS * DMODEL / 4) return;
  const int stride4 = MROWS * DMODEL / 4;
  float4 s = ((const float4*)part)[i];
  float4 p1 = ((const float4*)part)[i + stride4];
  float4 p2 = ((const float4*)part)[i + 2 * stride4];
  float4 p3 = ((const float4*)part)[i + 3 * stride4];
  float4 x = ((const float4*)xf)[i];
  s.x += p1.x + p2.x + p3.x + x.x;
  s.y += p1.y + p2.y + p3.y + x.y;
  s.z += p1.z + p2.z + p3.z + x.z;
  s.w += p1.w + p2.w + p3.w + x.w;
  ((float4*)xf)[i] = s;
  ushort4 o; o.x = f2bf(s.x); o.y = f2bf(s.y); o.z = f2bf(s.z); o.w = f2bf(s.w);
  ((ushort4*)xbf)[i] = o;
}

// ---------------------------------------------------------------- fused conv+SiLU+xproj+delta
__global__ __launch_bounds__(256) void convxproj_kern(
    const float* __restrict__ xz, const float* __restrict__ cw,
    const float* __restrict__ Wx, const float* __restrict__ wdt,
    const float* __restrict__ bdt,
    float* __restrict__ xs, float* __restrict__ dlt, float* __restrict__ bc)
{
  __shared__ float sx[DINNER];
  __shared__ float sxp[40];
  const int row = blockIdx.x;
  const int t = row & (SEQ - 1);
  const int tid = threadIdx.x;

  for (int c = tid; c < DINNER; c += 256) {
    const float* w = cw + c * DCONV;
    float a = 0.f;
#pragma unroll
    for (int k = 0; k < DCONV; ++k) {
      const int tt = t - (DCONV - 1) + k;
      if (tt >= 0) a += w[k] * xz[(long)(row - (DCONV - 1) + k) * (2 * DINNER) + c];
    }
    const float s = a / (1.f + __expf(-a));
    sx[c] = s;
    xs[(long)row * DINNER + c] = s;
  }
  __syncthreads();

  const int wv = tid >> 6, lane = tid & 63;
  for (int e = wv; e < 2 * DSTATE + 1; e += 4) {
    const float* We = Wx + (long)e * DINNER;
    float p = 0.f;
    for (int d = lane; d < DINNER; d += 64) p += sx[d] * We[d];
#pragma unroll
    for (int off = 32; off; off >>= 1) p += __shfl_xor(p, off, 64);
    if (lane == 0) sxp[e] = p;
  }
  __syncthreads();
  const float dtr = sxp[0];
  for (int d = tid; d < DINNER; d += 256) {
    float v = dtr * wdt[d] + bdt[d];
    float sp = (v > 15.f) ? v : log1pf(__expf(v));
    dlt[(long)row * DINNER + d] = sp;
  }
  if (tid < 2 * DSTATE) bc[(long)row * (2 * DSTATE) + tid] = sxp[1 + tid];
}

// ---------------------------------------------------------------- chunked selective scan + gate
__global__ __launch_bounds__(128) void scan_kern(
    const float* __restrict__ dlt, const float* __restrict__ bc,
    const float* __restrict__ xs, const float* __restrict__ xz,
    const float* __restrict__ alog, const float* __restrict__ dpar,
    u16* __restrict__ ybf)
{
  __shared__ float sh_h[16][8][DSTATE];
  __shared__ float sh_s[16][8];
  const int tid = threadIdx.x;
  const int ch = tid & 7, chunk = tid >> 3;
  const int ch_abs = blockIdx.x * 8 + ch;
  const int b = ch_abs / DINNER, d = ch_abs % DINNER;
  float An[DSTATE];
#pragma unroll
  for (int n = 0; n < DSTATE; ++n) An[n] = -__expf(alog[(long)d * DSTATE + n]);
  const int r0 = b * SEQ + chunk * 32;

  float h[DSTATE];
#pragma unroll
  for (int n = 0; n < DSTATE; ++n) h[n] = 0.f;
  float ssum = 0.f;
  for (int s = 0; s < 32; ++s) {
    const int row = r0 + s;
    const float dl = dlt[(long)row * DINNER + d];
    const float xv = xs[(long)row * DINNER + d];
    const float dx = dl * xv;
    const float4* bp = (const float4*)(bc + (long)row * (2 * DSTATE));
    float Bv[DSTATE];
    *(float4*)&Bv[0]  = bp[0]; *(float4*)&Bv[4]  = bp[1];
    *(float4*)&Bv[8]  = bp[2]; *(float4*)&Bv[12] = bp[3];
    ssum += dl;
#pragma unroll
    for (int n = 0; n < DSTATE; ++n) h[n] = __expf(dl * An[n]) * h[n] + dx * Bv[n];
  }
#pragma unroll
  for (int n = 0; n < DSTATE; ++n) sh_h[chunk][ch][n] = h[n];
  sh_s[chunk][ch] = ssum;
  __syncthreads();

  {
    const int n2 = tid & 15, ch2 = tid >> 4;
    const int d2 = (blockIdx.x * 8 + ch2) % DINNER;
    const float A2 = -__expf(alog[(long)d2 * DSTATE + n2]);
    float carry = 0.f;
    for (int c = 0; c < 16; ++c) {
      const float hl = sh_h[c][ch2][n2];
      sh_h[c][ch2][n2] = carry;
      carry = __expf(A2 * sh_s[c][ch2]) * carry + hl;
    }
  }
  __syncthreads();

#pragma unroll
  for (int n = 0; n < DSTATE; ++n) h[n] = sh_h[chunk][ch][n];
  const float dp = dpar[d];
  for (int s = 0; s < 32; ++s) {
    const int row = r0 + s;
    const float dl = dlt[(long)row * DINNER + d];
    const float xv = xs[(long)row * DINNER + d];
    const float dx = dl * xv;
    const float4* bp = (const float4*)(bc + (long)row * (2 * DSTATE));
    float Bv[DSTATE], Cv[DSTATE];
    *(float4*)&Bv[0]  = bp[0]; *(float4*)&Bv[4]  = bp[1];
    *(float4*)&Bv[8]  = bp[2]; *(float4*)&Bv[12] = bp[3];
    *(float4*)&Cv[0]  = bp[4]; *(float4*)&Cv[4]  = bp[5];
    *(float4*)&Cv[8]  = bp[6]; *(float4*)&Cv[12] = bp[7];
    float y = 0.f;
#pragma unroll
    for (int n = 0; n < DSTATE; ++n) {
      const float hn = __expf(dl * An[n]) * h[n] + dx * Bv[n];
      h[n] = hn;
      y += Cv[n] * hn;
    }
    y += dp * xv;
    const float zz = xz[(long)row * (2 * DINNER) + DINNER + d];
    const float o = y * (zz / (1.f + __expf(-zz)));
    ybf[(long)row * DINNER + d] = f2bf(o);
  }
}

// ---------------------------------------------------------------- fused last-redout + RMSNorm -> bf16
__global__ __launch_bounds__(256) void rmsfuse_kern(const float* __restrict__ part,
                                                    const float* __restrict__ xf,
                                                    const float* __restrict__ nw,
                                                    u16* __restrict__ xnbf) {
  const int row = blockIdx.x, tid = threadIdx.x;
  const int S = MROWS * DMODEL;
  float v[3];
  float p = 0.f;
#pragma unroll
  for (int k = 0; k < 3; ++k) {
    const int i = row * DMODEL + tid + k * 256;
    float x = xf[i] + part[i] + part[i + S] + part[i + 2 * S] + part[i + 3 * S];
    v[k] = x;
    p += x * x;
  }
#pragma unroll
  for (int off = 32; off; off >>= 1) p += __shfl_xor(p, off, 64);
  __shared__ float red[4];
  __shared__ float s_rms;
  const int wv = tid >> 6, lane = tid & 63;
  if (lane == 0) red[wv] = p;
  __syncthreads();
  if (tid == 0) {
    float tsum = red[0] + red[1] + red[2] + red[3];
    s_rms = rsqrtf(tsum / (float)DMODEL + 1e-5f);
  }
  __syncthreads();
  const float r = s_rms;
#pragma unroll
  for (int k = 0; k < 3; ++k) {
    const int dd = tid + k * 256;
    xnbf[(long)row * DMODEL + dd] = f2bf(v[k] * r * nw[dd]);
  }
}

// ---------------------------------------------------------------- host
extern "C" void kernel_launch(void* const* d_in, const int* in_sizes, int n_in,
                              void* d_out, int out_size, void* d_ws, size_t ws_size,
                              hipStream_t stream)
{
  (void)in_sizes; (void)n_in; (void)out_size; (void)ws_size;
  const int*   idx   = (const int*)  d_in[0];
  const float* emb   = (const float*)d_in[1];
  const float* W_in  = (const float*)d_in[2];
  const float* convw = (const float*)d_in[3];
  const float* W_xp  = (const float*)d_in[4];
  const float* W_dt  = (const float*)d_in[5];
  const float* b_dt  = (const float*)d_in[6];
  const float* a_log = (const float*)d_in[7];
  const float* d_par = (const float*)d_in[8];
  const float* W_out = (const float*)d_in[9];
  const float* normw = (const float*)d_in[10];
  float* out = (float*)d_out;

  char* ws = (char*)d_ws;
  size_t off = 0;
  auto alloc = [&](size_t bytes) -> void* {
    void* p = ws + off;
    off += (bytes + 255) & ~(size_t)255;
    return p;
  };
  u16*   embbf  = (u16*)  alloc((size_t)VPAD * DMODEL * 2);
  u16*   winbf  = (u16*)  alloc((size_t)NLAYER * 2 * DINNER * DMODEL * 2);
  u16*   woutbf = (u16*)  alloc((size_t)NLAYER * DMODEL * DINNER * 2);
  float* xf     = (float*)alloc((size_t)MROWS * DMODEL * 4);
  u16*   xbf    = (u16*)  alloc((size_t)MROWS * DMODEL * 2);
  float* xz     = (float*)alloc((size_t)MROWS * 2 * DINNER * 4);
  float* xs     = (float*)alloc((size_t)MROWS * DINNER * 4);
  float* dlt    = (float*)alloc((size_t)MROWS * DINNER * 4);
  float* bc     = (float*)alloc((size_t)MROWS * 2 * DSTATE * 4);
  u16*   ybf    = (u16*)  alloc((size_t)MROWS * DINNER * 2);
  u16*   xnbf   = (u16*)  alloc((size_t)MROWS * DMODEL * 2);
  float* part   = (float*)alloc((size_t)4 * MROWS * DMODEL * 4);

  prep_kern<<<2048, 256, 0, stream>>>(emb, W_in, W_out, idx, embbf, winbf, woutbf, xf, xbf);

  for (int l = 0; l < NLAYER; ++l) {
    gemm3_kern<false, true><<<8 * (2 * DINNER / 128), 256, 0, stream>>>(
        xbf, winbf + (size_t)l * 2 * DINNER * DMODEL, xz,
        MROWS, 2 * DINNER, DMODEL, DMODEL, DMODEL);
    convxproj_kern<<<MROWS, 256, 0, stream>>>(
        xz, convw + (size_t)l * DINNER * DCONV,
        W_xp + (size_t)l * (2 * DSTATE + 1) * DINNER,
        W_dt + (size_t)l * DINNER, b_dt + (size_t)l * DINNER, xs, dlt, bc);
    scan_kern<<<BATCH * DINNER / 8, 128, 0, stream>>>(
        dlt, bc, xs, xz, a_log + (size_t)l * DINNER * DSTATE, d_par + (size_t)l * DINNER, ybf);
    gemm3_kern<false, true><<<dim3(8 * (DMODEL / 128), 1, 4), 256, 0, stream>>>(
        ybf, woutbf + (size_t)l * DMODEL * DINNER, part,
        MROWS, DMODEL, DINNER / 4, DINNER, DINNER);
    if (l < NLAYER - 1)
      redout_kern<<<MROWS * DMODEL / 4 / 256, 256, 0, stream>>>(part, xf, xbf);
  }
  rmsfuse_kern<<<MROWS, 256, 0, stream>>>(part, xf, normw, xnbf);
  // logits = xn @ emb^T  (M=1024, N=50257, K=768), 256^2 4-phase pipelined
  gemm8_kern<<<4 * (VPAD / 256), 512, 0, stream>>>(
      xnbf, embbf, out, VV, DMODEL, DMODEL, DMODEL);
}